// Round 9
// baseline (858.415 us; speedup 1.0000x reference)
//
#include <hip/hip_runtime.h>
#include <hip/hip_cooperative_groups.h>
#include <math.h>

namespace cg = cooperative_groups;

// ---------------------------------------------------------------------------
// SimGNN forward on MI355X (gfx950).  R9: single cooperative kernel with 12
// grid.sync phases replaces 14 dispatches (R8 analysis: ~10us/dispatch gap
// dominated; kernels sum to ~95us of the 259us total).  Multi-kernel
// fallback preserved if cooperative launch is unavailable.
// ---------------------------------------------------------------------------

#define SIM_CHUNK 2
#define GS_PAD 16
#define GS_REP 8

using bf16x8 = __attribute__((ext_vector_type(8))) short;
using f32x4  = __attribute__((ext_vector_type(4))) float;

__device__ __forceinline__ unsigned short f2bf(float f) {  // RNE
    unsigned u = __float_as_uint(f);
    unsigned r = ((u >> 16) & 1u) + 0x7FFFu;
    return (unsigned short)((u + r) >> 16);
}

// ============================ cooperative mega-kernel =======================

struct CoopParams {
    const int *ei1, *ei2;
    const float *x1, *x2;
    const float *W1, *b1, *W2, *b2, *W3, *b3, *Wa;
    const float *Wt, *V, *bt;
    const float *fc1W, *fc1b, *fc2W, *fc2b, *fc3W, *fc3b, *scW, *scb, *avg_v;
    float* out;
    float* af; unsigned short* afbf; float* gsum; float* p12; int* cnt;
    float2* pbmm; unsigned* pbhist;
    float* dinv; int* offs; int* cursor; int* esrc;
    float* bufA; float* bufB;   // Y (2N*128), X (2N*128)
    float4* zbase; int zn4;
    int N, E;
};

// ---- agg phase: out[rs] = relu?(dt*(dt*h[rs]+sum ds*h[s])+b), rs over 2N ----
template <int F, bool RELU, bool BIAS, bool POOL>
__device__ __forceinline__ void aggPhase(const CoopParams& P, const float* h0,
                                         const float* h1, const float* bvec,
                                         float* out, int G) {
    constexpr int TPR = F / 4;
    constexpr int per = 256 / TPR;
    const int N = P.N, E = P.E;
    int fq = (threadIdx.x % TPR) * 4;
    __shared__ float ls[32];
    for (int rs0 = blockIdx.x * per; rs0 < 2 * N; rs0 += G * per) {
        int g = rs0 >= N;  // per | N  =>  uniform per block-pass
        int rs = rs0 + threadIdx.x / TPR;
        int r = rs - (g ? N : 0);
        const float* h = g ? h1 : h0;
        const int* offs = P.offs + g * (N + 1);
        const int* esrc = P.esrc + (size_t)g * E;
        const float* dinv = P.dinv + g * N;
        float dt = dinv[r];
        float4 hv = *(const float4*)&h[(size_t)r * F + fq];
        float ax = dt * hv.x, ay = dt * hv.y, az = dt * hv.z, aw = dt * hv.w;
        int e = offs[r], e1 = offs[r + 1];
        for (; e + 4 <= e1; e += 4) {
            int s0 = esrc[e], s1 = esrc[e + 1], s2 = esrc[e + 2], s3 = esrc[e + 3];
            float d0 = dinv[s0], d1 = dinv[s1], d2 = dinv[s2], d3 = dinv[s3];
            float4 v0 = *(const float4*)&h[(size_t)s0 * F + fq];
            float4 v1 = *(const float4*)&h[(size_t)s1 * F + fq];
            float4 v2 = *(const float4*)&h[(size_t)s2 * F + fq];
            float4 v3 = *(const float4*)&h[(size_t)s3 * F + fq];
            ax = fmaf(d0, v0.x, ax); ay = fmaf(d0, v0.y, ay);
            az = fmaf(d0, v0.z, az); aw = fmaf(d0, v0.w, aw);
            ax = fmaf(d1, v1.x, ax); ay = fmaf(d1, v1.y, ay);
            az = fmaf(d1, v1.z, az); aw = fmaf(d1, v1.w, aw);
            ax = fmaf(d2, v2.x, ax); ay = fmaf(d2, v2.y, ay);
            az = fmaf(d2, v2.z, az); aw = fmaf(d2, v2.w, aw);
            ax = fmaf(d3, v3.x, ax); ay = fmaf(d3, v3.y, ay);
            az = fmaf(d3, v3.z, az); aw = fmaf(d3, v3.w, aw);
        }
        for (; e < e1; ++e) {
            int s = esrc[e];
            float ds = dinv[s];
            float4 sv = *(const float4*)&h[(size_t)s * F + fq];
            ax = fmaf(ds, sv.x, ax); ay = fmaf(ds, sv.y, ay);
            az = fmaf(ds, sv.z, az); aw = fmaf(ds, sv.w, aw);
        }
        float bx = 0.f, by = 0.f, bz = 0.f, bw = 0.f;
        if (BIAS) { float4 bb = *(const float4*)&bvec[fq]; bx = bb.x; by = bb.y; bz = bb.z; bw = bb.w; }
        float4 v;
        v.x = fmaf(dt, ax, bx); v.y = fmaf(dt, ay, by);
        v.z = fmaf(dt, az, bz); v.w = fmaf(dt, aw, bw);
        if (RELU) {
            v.x = fmaxf(v.x, 0.f); v.y = fmaxf(v.y, 0.f);
            v.z = fmaxf(v.z, 0.f); v.w = fmaxf(v.w, 0.f);
        }
        *(float4*)&out[(size_t)rs * F + fq] = v;
        if (POOL) {
            unsigned short r4[4] = {f2bf(v.x), f2bf(v.y), f2bf(v.z), f2bf(v.w)};
            *(uint2*)&P.afbf[(size_t)rs * F + fq] = *(uint2*)r4;
            if (threadIdx.x < 32) ls[threadIdx.x] = 0.f;
            __syncthreads();
            atomicAdd(&ls[fq + 0], v.x); atomicAdd(&ls[fq + 1], v.y);
            atomicAdd(&ls[fq + 2], v.z); atomicAdd(&ls[fq + 3], v.w);
            __syncthreads();
            if (threadIdx.x < 32) {
                int rep = blockIdx.x & (GS_REP - 1);
                atomicAdd(&P.gsum[((g * GS_REP + rep) * 32 + threadIdx.x) * GS_PAD],
                          ls[threadIdx.x]);
            }
            __syncthreads();
        }
    }
}

// ---- gemm phase: out[2N,FOUT] = x[2N,FIN] @ W (+b, relu); KT=32 ----
template <int FIN, int FOUT, bool BIAS, bool RELU>
__device__ __forceinline__ void gemmPhase(const CoopParams& P, const float* x,
                                          const float* W, const float* bvec,
                                          float* out, float* SMEM, int G) {
    constexpr int KT = 32;
    constexpr int TN = FOUT / 16;
    float (*XL)[KT + 2] = (float(*)[KT + 2])SMEM;
    float* WL = SMEM + 64 * (KT + 2);
    int t = threadIdx.x, tc = t & 15, tr = t >> 4;
    int ntiles = (2 * P.N) / 64;
    for (int tile = blockIdx.x; tile < ntiles; tile += G) {
        size_t rb = (size_t)tile * 64;
        float acc[4][TN];
#pragma unroll
        for (int i = 0; i < 4; ++i)
#pragma unroll
            for (int j = 0; j < TN; ++j) acc[i][j] = BIAS ? bvec[tc * TN + j] : 0.f;
        for (int k0 = 0; k0 < FIN; k0 += KT) {
            __syncthreads();
            for (int i = t; i < KT * FOUT / 4; i += 256)
                ((float4*)WL)[i] = ((const float4*)(W + (size_t)k0 * FOUT))[i];
            for (int idx = t; idx < 64 * KT / 2; idx += 256) {
                int r = idx >> 4, c2 = idx & 15;
                *(float2*)&XL[r][c2 * 2] =
                    *(const float2*)&x[(rb + r) * FIN + k0 + c2 * 2];
            }
            __syncthreads();
#pragma unroll 4
            for (int k = 0; k < KT; ++k) {
                float a[4], bv[TN];
#pragma unroll
                for (int i = 0; i < 4; ++i) a[i] = XL[tr * 4 + i][k];
#pragma unroll
                for (int j = 0; j < TN; ++j) bv[j] = WL[k * FOUT + tc * TN + j];
#pragma unroll
                for (int i = 0; i < 4; ++i)
#pragma unroll
                    for (int j = 0; j < TN; ++j) acc[i][j] = fmaf(a[i], bv[j], acc[i][j]);
            }
        }
#pragma unroll
        for (int i = 0; i < 4; ++i) {
            size_t row = rb + tr * 4 + i;
            float* orow = &out[row * FOUT + tc * TN];
#pragma unroll
            for (int j = 0; j < TN; ++j) {
                float v = acc[i][j];
                if (RELU) v = fmaxf(v, 0.f);
                acc[i][j] = v;
            }
            if (TN == 8) {
                *(float4*)&orow[0] = make_float4(acc[i][0], acc[i][1], acc[i][2], acc[i][3]);
                *(float4*)&orow[4] = make_float4(acc[i][4], acc[i][5], acc[i][6], acc[i][7]);
            } else if (TN == 4) {
                *(float4*)&orow[0] = make_float4(acc[i][0], acc[i][1], acc[i][2], acc[i][3]);
            } else {
                *(float2*)&orow[0] = make_float2(acc[i][0], acc[i][1]);
            }
        }
    }
}

__global__ __launch_bounds__(256, 4) void gnn_coop(CoopParams P) {
    cg::grid_group grid = cg::this_grid();
    const int G = gridDim.x;
    const int bid = blockIdx.x;
    const int t = threadIdx.x;
    const int lane = t & 63, wv = t >> 6;
    const int N = P.N, E = P.E;

    __shared__ float SMEM[64 * 34 + 32 * 128];  // gemm XL+WL (25KB), reused
    __shared__ int s_wtot[4], s_wbase[4];
    __shared__ float s_cm[32], s_ctx[32];
    __shared__ float s_wsum[4][32];
    __shared__ float s_wmn[4], s_wmx[4];
    __shared__ float s_mnmx[2];
    __shared__ unsigned s_hs[16];
    __shared__ float s_p1[32], s_p2[32], s_scp[16][17], s_sc[16], s_sf[32], s_h1[16];
    __shared__ unsigned s_hist[16];

    // ---- P0: zero gsum|p12|cnt ----
    for (int i = bid * 256 + t; i < P.zn4; i += G * 256)
        P.zbase[i] = make_float4(0.f, 0.f, 0.f, 0.f);
    grid.sync();

    // ---- P1: count degrees ----
    for (int i = bid * 256 + t; i < 2 * E; i += G * 256) {
        int g = i >= E;
        int e = i - (g ? E : 0);
        const int* tgt = (g ? P.ei2 : P.ei1) + E;
        atomicAdd(&P.cnt[g * N + tgt[e]], 1);
    }
    grid.sync();

    // ---- P2: scan (blocks 0,1; 256 threads, chunk = N/256) ----
    if (bid < 2) {
        int g = bid;
        const int* cnt = P.cnt + g * N;
        int* offs = P.offs + g * (N + 1);
        int* cursor = P.cursor + g * N;
        float* dinv = P.dinv + g * N;
        int chunk = N >> 8;
        int base = t * chunk;
        int s = 0;
        for (int i = 0; i < chunk; ++i) s += cnt[base + i];
        int v = s;
#pragma unroll
        for (int d = 1; d < 64; d <<= 1) {
            int u = __shfl_up(v, d);
            if (lane >= d) v += u;
        }
        if (lane == 63) s_wtot[wv] = v;
        __syncthreads();
        if (t == 0) {
            int r = 0;
            for (int i = 0; i < 4; ++i) { s_wbase[i] = r; r += s_wtot[i]; }
            offs[N] = r;
        }
        __syncthreads();
        int run = s_wbase[wv] + (v - s);
        for (int i = 0; i < chunk; ++i) {
            int idx = base + i;
            int c = cnt[idx];
            offs[idx] = run;
            cursor[idx] = run;
            dinv[idx] = 1.0f / sqrtf((float)(c + 1));
            run += c;
        }
    }
    grid.sync();

    // ---- P3: scatter ----
    for (int i = bid * 256 + t; i < 2 * E; i += G * 256) {
        int g = i >= E;
        int e = i - (g ? E : 0);
        const int* ei = g ? P.ei2 : P.ei1;
        int tg = ei[E + e];
        int pos = atomicAdd(&P.cursor[g * N + tg], 1);
        P.esrc[(size_t)g * E + pos] = ei[e];
    }
    grid.sync();

    // buffer plan: X=bufB (t0,t1,t3), Y=bufA (h1,t2)
    float* t0 = P.bufB;
    float* h1 = P.bufA;
    float* t1 = P.bufB;
    float* t2 = P.bufA;
    float* t3 = P.bufB;

    // ---- P4: aggL1 (x -> t0, F=64, raw) ----
    aggPhase<64, false, false, false>(P, P.x1, P.x2, nullptr, t0, G);
    grid.sync();
    // ---- P5: gemm1 (t0 -> h1 = relu(t0 W1 + b1)) ----
    gemmPhase<64, 128, true, true>(P, t0, P.W1, P.b1, h1, SMEM, G);
    grid.sync();
    // ---- P6: gemm2 (h1 -> t1 = h1 W2) ----
    gemmPhase<128, 64, false, false>(P, h1, P.W2, nullptr, t1, SMEM, G);
    grid.sync();
    // ---- P7: aggL2 (t1 -> t2 = relu(A t1 + b2)) ----
    aggPhase<64, true, true, false>(P, t1, t1 + (size_t)N * 64, P.b2, t2, G);
    grid.sync();
    // ---- P8: gemm3 (t2 -> t3 = t2 W3) ----
    gemmPhase<64, 32, false, false>(P, t2, P.W3, nullptr, t3, SMEM, G);
    grid.sync();
    // ---- P9: aggL3 (t3 -> af = A t3 + b3) + pool gsum + bf16 mirror ----
    aggPhase<32, false, true, true>(P, t3, t3 + (size_t)N * 32, P.b3, P.af, G);
    grid.sync();

    // ---- P10: attention pool + sim min/max ----
    {
        // pool: 256 rows per block, grid-stride over 2N
        for (int r0 = bid * 256; r0 < 2 * N; r0 += G * 256) {
            int g = r0 >= N;
            int r = r0 + t - (g ? N : 0);
            if (t < 32) {
                float s = 0.f;
#pragma unroll
                for (int rep = 0; rep < GS_REP; ++rep)
                    s += P.gsum[((g * GS_REP + rep) * 32 + t) * GS_PAD];
                s_cm[t] = s / (float)N;
            }
            __syncthreads();
            if (t < 32) {
                float s = 0.f;
                for (int d = 0; d < 32; ++d) s = fmaf(s_cm[d], P.Wa[d * 32 + t], s);
                s_ctx[t] = tanhf(s);
            }
            __syncthreads();
            const float* af = P.af + (size_t)g * N * 32;
            float rowv[32];
            const float4* row = (const float4*)(af + (size_t)r * 32);
            float dot = 0.f;
#pragma unroll
            for (int q = 0; q < 8; ++q) {
                float4 v = row[q];
                rowv[q * 4 + 0] = v.x; rowv[q * 4 + 1] = v.y;
                rowv[q * 4 + 2] = v.z; rowv[q * 4 + 3] = v.w;
                dot = fmaf(v.x, s_ctx[q * 4 + 0], dot);
                dot = fmaf(v.y, s_ctx[q * 4 + 1], dot);
                dot = fmaf(v.z, s_ctx[q * 4 + 2], dot);
                dot = fmaf(v.w, s_ctx[q * 4 + 3], dot);
            }
            float att = 1.f / (1.f + expf(-dot));
#pragma unroll
            for (int f = 0; f < 32; ++f) {
                float v = att * rowv[f];
#pragma unroll
                for (int off = 1; off < 64; off <<= 1) v += __shfl_xor(v, off);
                if (lane == 0) s_wsum[wv][f] = v;
            }
            __syncthreads();
            if (t < 32) {
                float s = s_wsum[0][t] + s_wsum[1][t] + s_wsum[2][t] + s_wsum[3][t];
                atomicAdd(&P.p12[g * 32 + t], s);
            }
            __syncthreads();
        }
        // sim min/max over 2048 jobs (128 rows x 256 cols each)
        const unsigned short* a1 = P.afbf;
        const unsigned short* a2 = P.afbf + (size_t)N * 32;
        int nbx = N >> 7, nch = nbx >> 1, njobs = nbx * nch;
        int r16 = lane & 15, kg = (lane >> 4) << 3;
        float mnT = 1e30f, mxT = -1e30f;
        for (int job = bid; job < njobs; job += G) {
            int by = job / nch, ch = job - by * nch;
            const unsigned short* arow =
                a1 + ((size_t)(by * 128 + (wv >> 1) * 64 + r16)) * 32 + kg;
            bf16x8 afr[4];
#pragma unroll
            for (int m = 0; m < 4; ++m) afr[m] = *(const bf16x8*)(arow + m * 16 * 32);
#pragma unroll
            for (int tt = 0; tt < 2; ++tt) {
                int bx = ch * 2 + tt;
                const unsigned short* brow =
                    a2 + ((size_t)(bx * 128 + (wv & 1) * 64 + r16)) * 32 + kg;
                bf16x8 bfr[4];
#pragma unroll
                for (int n = 0; n < 4; ++n) bfr[n] = *(const bf16x8*)(brow + n * 16 * 32);
                f32x4 zero = {0.f, 0.f, 0.f, 0.f};
#pragma unroll
                for (int mh = 0; mh < 2; ++mh) {
                    f32x4 acc[2][4];
#pragma unroll
                    for (int m2 = 0; m2 < 2; ++m2)
#pragma unroll
                        for (int n = 0; n < 4; ++n)
                            acc[m2][n] = __builtin_amdgcn_mfma_f32_16x16x32_bf16(
                                afr[mh * 2 + m2], bfr[n], zero, 0, 0, 0);
#pragma unroll
                    for (int m2 = 0; m2 < 2; ++m2)
#pragma unroll
                        for (int n = 0; n < 4; ++n)
#pragma unroll
                            for (int e2 = 0; e2 < 4; ++e2) {
                                float vv = acc[m2][n][e2];
                                mnT = fminf(mnT, vv);
                                mxT = fmaxf(mxT, vv);
                            }
                }
            }
        }
#pragma unroll
        for (int off = 1; off < 64; off <<= 1) {
            mnT = fminf(mnT, __shfl_xor(mnT, off));
            mxT = fmaxf(mxT, __shfl_xor(mxT, off));
        }
        if (lane == 0) { s_wmn[wv] = mnT; s_wmx[wv] = mxT; }
        __syncthreads();
        if (t == 0) {
            float bmn = fminf(fminf(s_wmn[0], s_wmn[1]), fminf(s_wmn[2], s_wmn[3]));
            float bmx = fmaxf(fmaxf(s_wmx[0], s_wmx[1]), fmaxf(s_wmx[2], s_wmx[3]));
            P.pbmm[bid] = make_float2(bmn, bmx);
        }
    }
    grid.sync();

    // ---- P11: sim histogram (per-block reduce of pbmm, then bin) ----
    {
        float mn2 = 1e30f, mx2 = -1e30f;
        for (int i = t; i < G; i += 256) {
            float2 vv = P.pbmm[i];
            mn2 = fminf(mn2, vv.x);
            mx2 = fmaxf(mx2, vv.y);
        }
#pragma unroll
        for (int off = 1; off < 64; off <<= 1) {
            mn2 = fminf(mn2, __shfl_xor(mn2, off));
            mx2 = fmaxf(mx2, __shfl_xor(mx2, off));
        }
        if (lane == 0) { s_wmn[wv] = mn2; s_wmx[wv] = mx2; }
        __syncthreads();
        if (t == 0) {
            s_mnmx[0] = fminf(fminf(s_wmn[0], s_wmn[1]), fminf(s_wmn[2], s_wmn[3]));
            s_mnmx[1] = fmaxf(fmaxf(s_wmx[0], s_wmx[1]), fmaxf(s_wmx[2], s_wmx[3]));
        }
        if (t < 16) s_hs[t] = 0;
        __syncthreads();
        float mnv = s_mnmx[0], mxv = s_mnmx[1];
        float width = (mxv > mnv) ? (mxv - mnv) : 1.0f;
        float scale = 16.0f / width;
        float nbias = -mnv * scale;

        const unsigned short* a1 = P.afbf;
        const unsigned short* a2 = P.afbf + (size_t)N * 32;
        int nbx = N >> 7, nch = nbx >> 1, njobs = nbx * nch;
        int r16 = lane & 15, kg = (lane >> 4) << 3;
        for (int job = bid; job < njobs; job += G) {
            int by = job / nch, ch = job - by * nch;
            const unsigned short* arow =
                a1 + ((size_t)(by * 128 + (wv >> 1) * 64 + r16)) * 32 + kg;
            bf16x8 afr[4];
#pragma unroll
            for (int m = 0; m < 4; ++m) afr[m] = *(const bf16x8*)(arow + m * 16 * 32);
            unsigned h40 = 0, h41 = 0, h42 = 0, h43 = 0;
#pragma unroll
            for (int tt = 0; tt < 2; ++tt) {
                int bx = ch * 2 + tt;
                const unsigned short* brow =
                    a2 + ((size_t)(bx * 128 + (wv & 1) * 64 + r16)) * 32 + kg;
                bf16x8 bfr[4];
#pragma unroll
                for (int n = 0; n < 4; ++n) bfr[n] = *(const bf16x8*)(brow + n * 16 * 32);
                f32x4 zero = {0.f, 0.f, 0.f, 0.f};
#pragma unroll
                for (int mh = 0; mh < 2; ++mh) {
                    f32x4 acc[2][4];
#pragma unroll
                    for (int m2 = 0; m2 < 2; ++m2)
#pragma unroll
                        for (int n = 0; n < 4; ++n)
                            acc[m2][n] = __builtin_amdgcn_mfma_f32_16x16x32_bf16(
                                afr[mh * 2 + m2], bfr[n], zero, 0, 0, 0);
#pragma unroll
                    for (int m2 = 0; m2 < 2; ++m2)
#pragma unroll
                        for (int n = 0; n < 4; ++n)
#pragma unroll
                            for (int e2 = 0; e2 < 4; ++e2) {
                                float vv = acc[m2][n][e2];
                                int bin = (int)fmaf(vv, scale, nbias);
                                bin = bin < 0 ? 0 : (bin > 15 ? 15 : bin);
                                unsigned wbit = 1u << ((bin & 3) << 3);
                                int hi = bin >> 2;
                                h40 += (hi == 0) ? wbit : 0u;
                                h41 += (hi == 1) ? wbit : 0u;
                                h42 += (hi == 2) ? wbit : 0u;
                                h43 += (hi == 3) ? wbit : 0u;
                            }
                }
            }
            unsigned hh[8];
            hh[0] = h40 & 0x00FF00FFu; hh[1] = (h40 >> 8) & 0x00FF00FFu;
            hh[2] = h41 & 0x00FF00FFu; hh[3] = (h41 >> 8) & 0x00FF00FFu;
            hh[4] = h42 & 0x00FF00FFu; hh[5] = (h42 >> 8) & 0x00FF00FFu;
            hh[6] = h43 & 0x00FF00FFu; hh[7] = (h43 >> 8) & 0x00FF00FFu;
#pragma unroll
            for (int off = 1; off < 64; off <<= 1) {
#pragma unroll
                for (int q = 0; q < 8; ++q) hh[q] += (unsigned)__shfl_xor((int)hh[q], off);
            }
            if (lane < 16) {
                int q = lane >> 2, rr = lane & 3;
                unsigned word = hh[2 * q + (rr & 1)];
                unsigned val = (rr < 2) ? (word & 0xFFFFu) : (word >> 16);
                atomicAdd(&s_hs[lane], val);
            }
        }
        __syncthreads();
        if (t < 16) P.pbhist[(size_t)bid * 16 + t] = s_hs[t];
    }
    grid.sync();

    // ---- P12: hist reduce + NTN + MLP head (block 0) ----
    if (bid == 0) {
        if (t < 16) s_hist[t] = 0;
        if (t < 32) s_p1[t] = P.p12[t];
        else if (t < 64) s_p2[t - 32] = P.p12[t];
        __syncthreads();
        {
            const uint4* pb = (const uint4*)P.pbhist;
            int total = G * 4;
            uint4 a = {0u, 0u, 0u, 0u};
            for (int i = t; i < total; i += 256) {
                uint4 v = pb[i];
                a.x += v.x; a.y += v.y; a.z += v.z; a.w += v.w;
            }
#pragma unroll
            for (int off = 4; off < 64; off <<= 1) {
                a.x += (unsigned)__shfl_xor((int)a.x, off);
                a.y += (unsigned)__shfl_xor((int)a.y, off);
                a.z += (unsigned)__shfl_xor((int)a.z, off);
                a.w += (unsigned)__shfl_xor((int)a.w, off);
            }
            if (lane < 4) {
                atomicAdd(&s_hist[lane * 4 + 0], a.x);
                atomicAdd(&s_hist[lane * 4 + 1], a.y);
                atomicAdd(&s_hist[lane * 4 + 2], a.z);
                atomicAdd(&s_hist[lane * 4 + 3], a.w);
            }
        }
        {
            int k = t & 15, dp = t >> 4;
            float s = 0.f;
#pragma unroll
            for (int dd = 0; dd < 2; ++dd) {
                int d = dp * 2 + dd;
                float a = s_p1[d];
                for (int e2 = 0; e2 < 32; ++e2)
                    s = fmaf(a * s_p2[e2], P.Wt[(d * 32 + e2) * 16 + k], s);
            }
            s_scp[dp][k] = s;
        }
        __syncthreads();
        if (t < 16) {
            float s = 0.f;
#pragma unroll
            for (int dp = 0; dp < 16; ++dp) s += s_scp[dp][t];
            float bl = 0.f;
            for (int m = 0; m < 32; ++m) bl = fmaf(P.V[t * 64 + m], s_p1[m], bl);
            for (int m = 0; m < 32; ++m) bl = fmaf(P.V[t * 64 + 32 + m], s_p2[m], bl);
            s_sc[t] = fmaxf(s + bl + P.bt[t], 0.f);
        }
        __syncthreads();
        if (t < 16) s_sf[t] = s_sc[t];
        if (t == 16) {
            unsigned tot = 0;
            for (int b = 0; b < 16; ++b) tot += s_hist[b];
            float ftot = (float)tot;
            for (int b = 0; b < 16; ++b) s_sf[16 + b] = (float)s_hist[b] / ftot;
        }
        __syncthreads();
        if (t < 16) {
            float a = P.fc1b[t];
            for (int m = 0; m < 32; ++m) a = fmaf(s_sf[m], P.fc1W[m * 16 + t], a);
            s_h1[t] = fmaxf(a, 0.f);
        }
        __syncthreads();
        if (t == 0) {
            float h2[8];
            for (int r = 0; r < 8; ++r) {
                float a = P.fc2b[r];
                for (int m = 0; m < 16; ++m) a = fmaf(s_h1[m], P.fc2W[m * 8 + r], a);
                h2[r] = fmaxf(a, 0.f);
            }
            float h3[4];
            for (int r = 0; r < 4; ++r) {
                float a = P.fc3b[r];
                for (int m = 0; m < 8; ++m) a = fmaf(h2[m], P.fc3W[m * 4 + r], a);
                h3[r] = fmaxf(a, 0.f);
            }
            float z = P.scb[0];
            for (int m = 0; m < 4; ++m) z = fmaf(h3[m], P.scW[m], z);
            float sig = 1.f / (1.f + expf(-z));
            P.out[0] = sig;
            P.out[1] = -logf(sig) * P.avg_v[0];
        }
    }
}

// ============================ fallback kernels (R8, proven) =================

__global__ void zero_ws(float4* __restrict__ p, int n4) {
    int i = blockIdx.x * 256 + threadIdx.x;
    if (i < n4) p[i] = make_float4(0.f, 0.f, 0.f, 0.f);
}

__global__ void count_tgt(const int* __restrict__ t0, const int* __restrict__ t1,
                          int* __restrict__ cnt, int N, int E) {
    int g = blockIdx.y;
    const int* t = g ? t1 : t0;
    int i = blockIdx.x * 256 + threadIdx.x;
    if (i < E) atomicAdd(&cnt[g * N + t[i]], 1);
}

__global__ __launch_bounds__(1024) void scan_offsets(const int* __restrict__ cnt_,
                                                     int* __restrict__ offs_,
                                                     int* __restrict__ cursor_,
                                                     float* __restrict__ dinv_, int N) {
    int g = blockIdx.x;
    const int* cnt = cnt_ + g * N;
    int* offs = offs_ + g * (N + 1);
    int* cursor = cursor_ + g * N;
    float* dinv = dinv_ + g * N;
    int tid = threadIdx.x, lane = tid & 63, wid = tid >> 6;
    int chunk = (N + 1023) >> 10;
    int base = tid * chunk;
    int s = 0;
    for (int i = 0; i < chunk; ++i) {
        int idx = base + i;
        if (idx < N) s += cnt[idx];
    }
    int v = s;
#pragma unroll
    for (int d = 1; d < 64; d <<= 1) {
        int u = __shfl_up(v, d);
        if (lane >= d) v += u;
    }
    __shared__ int wtot[16], wbase[16];
    if (lane == 63) wtot[wid] = v;
    __syncthreads();
    if (tid == 0) {
        int r = 0;
        for (int i = 0; i < 16; ++i) { wbase[i] = r; r += wtot[i]; }
        offs[N] = r;
    }
    __syncthreads();
    int run = wbase[wid] + (v - s);
    for (int i = 0; i < chunk; ++i) {
        int idx = base + i;
        if (idx < N) {
            int c = cnt[idx];
            offs[idx] = run;
            cursor[idx] = run;
            dinv[idx] = 1.0f / sqrtf((float)(c + 1));
            run += c;
        }
    }
}

__global__ void scatter_src(const int* __restrict__ s0, const int* __restrict__ s1,
                            const int* __restrict__ t0, const int* __restrict__ t1,
                            int* __restrict__ cursor, int* __restrict__ esrc, int N, int E) {
    int g = blockIdx.y;
    const int* src = g ? s1 : s0;
    const int* tgt = g ? t1 : t0;
    int i = blockIdx.x * 256 + threadIdx.x;
    if (i < E) {
        int t = tgt[i];
        int pos = atomicAdd(&cursor[g * N + t], 1);
        esrc[g * E + pos] = src[i];
    }
}

template <int FIN, int FOUT, bool BIAS, bool RELU>
__global__ __launch_bounds__(256, 2) void tiled_gemm(const float* __restrict__ x0,
                                                     const float* __restrict__ x1,
                                                     const float* __restrict__ W,
                                                     const float* __restrict__ b,
                                                     float* __restrict__ out,
                                                     size_t ostride, int N) {
    constexpr int KT = 64;
    constexpr int TN = FOUT / 16;
    int g = blockIdx.y;
    const float* x = g ? x1 : x0;
    out += (size_t)g * ostride;
    __shared__ float XL[64][KT + 2];
    __shared__ float WL[KT * FOUT];
    int t = threadIdx.x;
    int tc = t & 15, tr = t >> 4;
    int rb = blockIdx.x * 64;
    float acc[4][TN];
#pragma unroll
    for (int i = 0; i < 4; ++i)
#pragma unroll
        for (int j = 0; j < TN; ++j) acc[i][j] = BIAS ? b[tc * TN + j] : 0.f;
    for (int k0 = 0; k0 < FIN; k0 += KT) {
        if (k0) __syncthreads();
        constexpr int W4 = KT * FOUT / 4;
        const float4* Wsrc = (const float4*)(W + (size_t)k0 * FOUT);
#pragma unroll
        for (int i = t; i < W4; i += 256) ((float4*)WL)[i] = Wsrc[i];
#pragma unroll
        for (int idx = t; idx < 64 * KT / 2; idx += 256) {
            int r = idx >> 5, c2 = idx & 31;
            *(float2*)&XL[r][c2 * 2] = *(const float2*)&x[(size_t)(rb + r) * FIN + k0 + c2 * 2];
        }
        __syncthreads();
#pragma unroll 4
        for (int k = 0; k < KT; ++k) {
            float a[4], bv[TN];
#pragma unroll
            for (int i = 0; i < 4; ++i) a[i] = XL[tr * 4 + i][k];
#pragma unroll
            for (int j = 0; j < TN; ++j) bv[j] = WL[k * FOUT + tc * TN + j];
#pragma unroll
            for (int i = 0; i < 4; ++i)
#pragma unroll
                for (int j = 0; j < TN; ++j) acc[i][j] = fmaf(a[i], bv[j], acc[i][j]);
        }
    }
#pragma unroll
    for (int i = 0; i < 4; ++i) {
        int row = rb + tr * 4 + i;
        float* orow = &out[(size_t)row * FOUT + tc * TN];
#pragma unroll
        for (int j = 0; j < TN; ++j) {
            float v = acc[i][j];
            if (RELU) v = fmaxf(v, 0.f);
            acc[i][j] = v;
        }
        if (TN == 8) {
            *(float4*)&orow[0] = make_float4(acc[i][0], acc[i][1], acc[i][2], acc[i][3]);
            *(float4*)&orow[4] = make_float4(acc[i][4], acc[i][5], acc[i][6], acc[i][7]);
        } else if (TN == 4) {
            *(float4*)&orow[0] = make_float4(acc[i][0], acc[i][1], acc[i][2], acc[i][3]);
        } else {
            *(float2*)&orow[0] = make_float2(acc[i][0], acc[i][1]);
        }
    }
}

template <int F, bool RELU, bool POOL, bool BIAS>
__global__ __launch_bounds__(256) void agg_csr(const float* __restrict__ h0,
                                               const float* __restrict__ h1,
                                               const int* __restrict__ offs_,
                                               const int* __restrict__ esrc_,
                                               const float* __restrict__ dinv_,
                                               const float* __restrict__ b,
                                               float* __restrict__ out, size_t ostride,
                                               unsigned short* __restrict__ outbf,
                                               size_t obfstride,
                                               float* __restrict__ gsum, int N, int E) {
    int g = blockIdx.y;
    const float* h = g ? h1 : h0;
    const int* offs = offs_ + g * (N + 1);
    const int* esrc = esrc_ + g * E;
    const float* dinv = dinv_ + g * N;
    out += (size_t)g * ostride;
    constexpr int TPR = F / 4;
    constexpr int RPB = 256 / TPR;
    int fq = (threadIdx.x % TPR) * 4;
    int t = blockIdx.x * RPB + threadIdx.x / TPR;
    float4 v = {0.f, 0.f, 0.f, 0.f};
    if (t < N) {
        float dt = dinv[t];
        float4 hv = *(const float4*)&h[(size_t)t * F + fq];
        float ax = dt * hv.x, ay = dt * hv.y, az = dt * hv.z, aw = dt * hv.w;
        int e = offs[t], e1 = offs[t + 1];
        for (; e + 4 <= e1; e += 4) {
            int s0 = esrc[e], s1 = esrc[e + 1], s2 = esrc[e + 2], s3 = esrc[e + 3];
            float d0 = dinv[s0], d1 = dinv[s1], d2 = dinv[s2], d3 = dinv[s3];
            float4 v0 = *(const float4*)&h[(size_t)s0 * F + fq];
            float4 v1 = *(const float4*)&h[(size_t)s1 * F + fq];
            float4 v2 = *(const float4*)&h[(size_t)s2 * F + fq];
            float4 v3 = *(const float4*)&h[(size_t)s3 * F + fq];
            ax = fmaf(d0, v0.x, ax); ay = fmaf(d0, v0.y, ay);
            az = fmaf(d0, v0.z, az); aw = fmaf(d0, v0.w, aw);
            ax = fmaf(d1, v1.x, ax); ay = fmaf(d1, v1.y, ay);
            az = fmaf(d1, v1.z, az); aw = fmaf(d1, v1.w, aw);
            ax = fmaf(d2, v2.x, ax); ay = fmaf(d2, v2.y, ay);
            az = fmaf(d2, v2.z, az); aw = fmaf(d2, v2.w, aw);
            ax = fmaf(d3, v3.x, ax); ay = fmaf(d3, v3.y, ay);
            az = fmaf(d3, v3.z, az); aw = fmaf(d3, v3.w, aw);
        }
        for (; e < e1; ++e) {
            int s = esrc[e];
            float ds = dinv[s];
            float4 sv = *(const float4*)&h[(size_t)s * F + fq];
            ax = fmaf(ds, sv.x, ax); ay = fmaf(ds, sv.y, ay);
            az = fmaf(ds, sv.z, az); aw = fmaf(ds, sv.w, aw);
        }
        float4 bb = {0.f, 0.f, 0.f, 0.f};
        if (BIAS) bb = *(const float4*)&b[fq];
        v.x = fmaf(dt, ax, bb.x); v.y = fmaf(dt, ay, bb.y);
        v.z = fmaf(dt, az, bb.z); v.w = fmaf(dt, aw, bb.w);
        if (RELU) {
            v.x = fmaxf(v.x, 0.f); v.y = fmaxf(v.y, 0.f);
            v.z = fmaxf(v.z, 0.f); v.w = fmaxf(v.w, 0.f);
        }
        *(float4*)&out[(size_t)t * F + fq] = v;
    }
    if (POOL) {
        if (t < N) {
            unsigned short r4[4] = {f2bf(v.x), f2bf(v.y), f2bf(v.z), f2bf(v.w)};
            *(uint2*)&outbf[(size_t)g * obfstride + (size_t)t * F + fq] = *(uint2*)r4;
        }
        __shared__ float ls[F];
        if (threadIdx.x < F) ls[threadIdx.x] = 0.f;
        __syncthreads();
        atomicAdd(&ls[fq + 0], v.x);
        atomicAdd(&ls[fq + 1], v.y);
        atomicAdd(&ls[fq + 2], v.z);
        atomicAdd(&ls[fq + 3], v.w);
        __syncthreads();
        if (threadIdx.x < 32) {
            int rep = blockIdx.x & (GS_REP - 1);
            atomicAdd(&gsum[((g * GS_REP + rep) * 32 + threadIdx.x) * GS_PAD],
                      ls[threadIdx.x]);
        }
    }
}

__global__ __launch_bounds__(256) void pool_att(const float* __restrict__ af,
                                                const float* __restrict__ gsum,
                                                const float* __restrict__ Wa,
                                                float* __restrict__ p12, int N) {
    int g = blockIdx.y;
    af += (size_t)g * N * 32;
    __shared__ float cm[32], ctxs[32];
    int tid = threadIdx.x;
    if (tid < 32) {
        float s = 0.f;
#pragma unroll
        for (int r = 0; r < GS_REP; ++r) s += gsum[((g * GS_REP + r) * 32 + tid) * GS_PAD];
        cm[tid] = s / (float)N;
    }
    __syncthreads();
    if (tid < 32) {
        float s = 0.f;
        for (int d = 0; d < 32; ++d) s = fmaf(cm[d], Wa[d * 32 + tid], s);
        ctxs[tid] = tanhf(s);
    }
    __syncthreads();
    int r = blockIdx.x * 256 + tid;
    float rowv[32];
    float att = 0.f;
    if (r < N) {
        const float4* row = (const float4*)(af + (size_t)r * 32);
        float dot = 0.f;
#pragma unroll
        for (int q = 0; q < 8; ++q) {
            float4 v = row[q];
            rowv[q * 4 + 0] = v.x; rowv[q * 4 + 1] = v.y;
            rowv[q * 4 + 2] = v.z; rowv[q * 4 + 3] = v.w;
            dot = fmaf(v.x, ctxs[q * 4 + 0], dot);
            dot = fmaf(v.y, ctxs[q * 4 + 1], dot);
            dot = fmaf(v.z, ctxs[q * 4 + 2], dot);
            dot = fmaf(v.w, ctxs[q * 4 + 3], dot);
        }
        att = 1.f / (1.f + expf(-dot));
    } else {
#pragma unroll
        for (int f = 0; f < 32; ++f) rowv[f] = 0.f;
    }
    __shared__ float wsum[4][32];
    int lane = tid & 63, wid = tid >> 6;
#pragma unroll
    for (int f = 0; f < 32; ++f) {
        float v = att * rowv[f];
#pragma unroll
        for (int off = 1; off < 64; off <<= 1) v += __shfl_xor(v, off);
        if (lane == 0) wsum[wid][f] = v;
    }
    __syncthreads();
    if (tid < 32) {
        float s = wsum[0][tid] + wsum[1][tid] + wsum[2][tid] + wsum[3][tid];
        atomicAdd(&p12[g * 32 + tid], s);
    }
}

template <bool HIST>
__global__ __launch_bounds__(256) void sim_mfma(const unsigned short* __restrict__ a1,
                                                const unsigned short* __restrict__ a2,
                                                int N, int nblk,
                                                float2* __restrict__ pbmm,
                                                unsigned* __restrict__ pbhist) {
    int nb = N >> 7;
    int nchunk = nb / SIM_CHUNK;
    int by = blockIdx.x / nchunk;
    int ch = blockIdx.x % nchunk;
    int w = threadIdx.x >> 6, lane = threadIdx.x & 63;
    int r16 = lane & 15, kg = (lane >> 4) << 3;
    __shared__ unsigned hs[16];
    __shared__ float mnmx[2];
    if (HIST && threadIdx.x < 16) hs[threadIdx.x] = 0;
    float scale = 0.f, nbias = 0.f;
    if (HIST) {
        float mn2 = 1e30f, mx2 = -1e30f;
        for (int i = threadIdx.x; i < nblk; i += 256) {
            float2 vv = pbmm[i];
            mn2 = fminf(mn2, vv.x);
            mx2 = fmaxf(mx2, vv.y);
        }
#pragma unroll
        for (int off = 1; off < 64; off <<= 1) {
            mn2 = fminf(mn2, __shfl_xor(mn2, off));
            mx2 = fmaxf(mx2, __shfl_xor(mx2, off));
        }
        __shared__ float wmn2[4], wmx2[4];
        if (lane == 0) { wmn2[w] = mn2; wmx2[w] = mx2; }
        __syncthreads();
        if (threadIdx.x == 0) {
            mnmx[0] = fminf(fminf(wmn2[0], wmn2[1]), fminf(wmn2[2], wmn2[3]));
            mnmx[1] = fmaxf(fmaxf(wmx2[0], wmx2[1]), fmaxf(wmx2[2], wmx2[3]));
        }
        __syncthreads();
        float mnv = mnmx[0], mxv = mnmx[1];
        float width = (mxv > mnv) ? (mxv - mnv) : 1.0f;
        scale = 16.0f / width;
        nbias = -mnv * scale;
    }
    const unsigned short* arow = a1 + ((size_t)(by * 128 + (w >> 1) * 64 + r16)) * 32 + kg;
    bf16x8 afr[4];
#pragma unroll
    for (int m = 0; m < 4; ++m) afr[m] = *(const bf16x8*)(arow + m * 16 * 32);
    float mn = 1e30f, mx = -1e30f;
    unsigned h4_0 = 0, h4_1 = 0, h4_2 = 0, h4_3 = 0;
#pragma unroll
    for (int t = 0; t < SIM_CHUNK; ++t) {
        int bx = ch * SIM_CHUNK + t;
        const unsigned short* brow = a2 + ((size_t)(bx * 128 + (w & 1) * 64 + r16)) * 32 + kg;
        bf16x8 bfr[4];
#pragma unroll
        for (int n = 0; n < 4; ++n) bfr[n] = *(const bf16x8*)(brow + n * 16 * 32);
        f32x4 zero = {0.f, 0.f, 0.f, 0.f};
        f32x4 acc[4][4];
#pragma unroll
        for (int m = 0; m < 4; ++m)
#pragma unroll
            for (int n = 0; n < 4; ++n)
                acc[m][n] = __builtin_amdgcn_mfma_f32_16x16x32_bf16(afr[m], bfr[n], zero, 0, 0, 0);
        if (!HIST) {
#pragma unroll
            for (int m = 0; m < 4; ++m)
#pragma unroll
                for (int n = 0; n < 4; ++n)
#pragma unroll
                    for (int e = 0; e < 4; ++e) {
                        float v = acc[m][n][e];
                        mn = fminf(mn, v);
                        mx = fmaxf(mx, v);
                    }
        } else {
#pragma unroll
            for (int m = 0; m < 4; ++m)
#pragma unroll
                for (int n = 0; n < 4; ++n)
#pragma unroll
                    for (int e = 0; e < 4; ++e) {
                        float v = acc[m][n][e];
                        int bin = (int)fmaf(v, scale, nbias);
                        bin = bin < 0 ? 0 : (bin > 15 ? 15 : bin);
                        unsigned wbit = 1u << ((bin & 3) << 3);
                        int hi = bin >> 2;
                        h4_0 += (hi == 0) ? wbit : 0u;
                        h4_1 += (hi == 1) ? wbit : 0u;
                        h4_2 += (hi == 2) ? wbit : 0u;
                        h4_3 += (hi == 3) ? wbit : 0u;
                    }
        }
    }
    if (!HIST) {
#pragma unroll
        for (int off = 1; off < 64; off <<= 1) {
            mn = fminf(mn, __shfl_xor(mn, off));
            mx = fmaxf(mx, __shfl_xor(mx, off));
        }
        __shared__ float wmn[4], wmx[4];
        if (lane == 0) { wmn[w] = mn; wmx[w] = mx; }
        __syncthreads();
        if (threadIdx.x == 0) {
            float bmn = fminf(fminf(wmn[0], wmn[1]), fminf(wmn[2], wmn[3]));
            float bmx = fmaxf(fmaxf(wmx[0], wmx[1]), fmaxf(wmx[2], wmx[3]));
            pbmm[blockIdx.x] = make_float2(bmn, bmx);
        }
    } else {
        unsigned hh[8];
        hh[0] = h4_0 & 0x00FF00FFu; hh[1] = (h4_0 >> 8) & 0x00FF00FFu;
        hh[2] = h4_1 & 0x00FF00FFu; hh[3] = (h4_1 >> 8) & 0x00FF00FFu;
        hh[4] = h4_2 & 0x00FF00FFu; hh[5] = (h4_2 >> 8) & 0x00FF00FFu;
        hh[6] = h4_3 & 0x00FF00FFu; hh[7] = (h4_3 >> 8) & 0x00FF00FFu;
#pragma unroll
        for (int off = 1; off < 64; off <<= 1) {
#pragma unroll
            for (int q = 0; q < 8; ++q) hh[q] += (unsigned)__shfl_xor((int)hh[q], off);
        }
        __syncthreads();
        if (lane < 16) {
            int q = lane >> 2, r = lane & 3;
            unsigned word = hh[2 * q + (r & 1)];
            unsigned val = (r < 2) ? (word & 0xFFFFu) : (word >> 16);
            atomicAdd(&hs[lane], val);
        }
        __syncthreads();
        if (threadIdx.x < 16)
            pbhist[(size_t)blockIdx.x * 16 + threadIdx.x] = hs[threadIdx.x];
    }
}

__global__ __launch_bounds__(256) void ntn_final(
    const float* __restrict__ p12, const float* __restrict__ Wt,
    const float* __restrict__ V, const float* __restrict__ bt,
    const unsigned* __restrict__ pbhist, int nblk,
    const float* __restrict__ fc1W, const float* __restrict__ fc1b,
    const float* __restrict__ fc2W, const float* __restrict__ fc2b,
    const float* __restrict__ fc3W, const float* __restrict__ fc3b,
    const float* __restrict__ scW, const float* __restrict__ scb,
    const float* __restrict__ avg_v, float* __restrict__ out) {
    __shared__ float p1l[32], p2l[32];
    __shared__ float scp[16][17];
    __shared__ unsigned hs[16];
    __shared__ float sc[16];
    __shared__ float sfeat[32];
    __shared__ float h1s[16];
    int t = threadIdx.x;
    if (t < 16) hs[t] = 0;
    if (t < 32) p1l[t] = p12[t];
    else if (t < 64) p2l[t - 32] = p12[t];
    __syncthreads();
    {
        const uint4* pb = (const uint4*)pbhist;
        int total = nblk * 4;
        uint4 a = {0u, 0u, 0u, 0u};
        for (int i = t; i < total; i += 256) {
            uint4 v = pb[i];
            a.x += v.x; a.y += v.y; a.z += v.z; a.w += v.w;
        }
#pragma unroll
        for (int off = 4; off < 64; off <<= 1) {
            a.x += (unsigned)__shfl_xor((int)a.x, off);
            a.y += (unsigned)__shfl_xor((int)a.y, off);
            a.z += (unsigned)__shfl_xor((int)a.z, off);
            a.w += (unsigned)__shfl_xor((int)a.w, off);
        }
        int lane = t & 63;
        if (lane < 4) {
            atomicAdd(&hs[lane * 4 + 0], a.x);
            atomicAdd(&hs[lane * 4 + 1], a.y);
            atomicAdd(&hs[lane * 4 + 2], a.z);
            atomicAdd(&hs[lane * 4 + 3], a.w);
        }
    }
    {
        int k = t & 15, dp = t >> 4;
        float s = 0.f;
#pragma unroll
        for (int dd = 0; dd < 2; ++dd) {
            int d = dp * 2 + dd;
            float a = p1l[d];
            for (int e = 0; e < 32; ++e)
                s = fmaf(a * p2l[e], Wt[(d * 32 + e) * 16 + k], s);
        }
        scp[dp][k] = s;
    }
    __syncthreads();
    if (t < 16) {
        float s = 0.f;
#pragma unroll
        for (int dp = 0; dp < 16; ++dp) s += scp[dp][t];
        float bl = 0.f;
        for (int m = 0; m < 32; ++m) bl = fmaf(V[t * 64 + m], p1l[m], bl);
        for (int m = 0; m < 32; ++m) bl = fmaf(V[t * 64 + 32 + m], p2l[m], bl);
        sc[t] = fmaxf(s + bl + bt[t], 0.f);
    }
    __syncthreads();
    if (t < 16) sfeat[t] = sc[t];
    if (t == 16) {
        unsigned tot = 0;
        for (int b = 0; b < 16; ++b) tot += hs[b];
        float ftot = (float)tot;
        for (int b = 0; b < 16; ++b) sfeat[16 + b] = (float)hs[b] / ftot;
    }
    __syncthreads();
    if (t < 16) {
        float a = fc1b[t];
        for (int m = 0; m < 32; ++m) a = fmaf(sfeat[m], fc1W[m * 16 + t], a);
        h1s[t] = fmaxf(a, 0.f);
    }
    __syncthreads();
    if (t != 0) return;
    float h2[8];
    for (int r = 0; r < 8; ++r) {
        float a = fc2b[r];
        for (int m = 0; m < 16; ++m) a = fmaf(h1s[m], fc2W[m * 8 + r], a);
        h2[r] = fmaxf(a, 0.f);
    }
    float h3[4];
    for (int r = 0; r < 4; ++r) {
        float a = fc3b[r];
        for (int m = 0; m < 8; ++m) a = fmaf(h2[m], fc3W[m * 4 + r], a);
        h3[r] = fmaxf(a, 0.f);
    }
    float z = scb[0];
    for (int m = 0; m < 4; ++m) z = fmaf(h3[m], scW[m], z);
    float sig = 1.f / (1.f + expf(-z));
    out[0] = sig;
    out[1] = -logf(sig) * avg_v[0];
}

// ---------------------------------------------------------------------------
extern "C" void kernel_launch(void* const* d_in, const int* in_sizes, int n_in,
                              void* d_out, int out_size, void* d_ws, size_t ws_size,
                              hipStream_t stream) {
    (void)n_in; (void)out_size;
    const int* ei1 = (const int*)d_in[0];
    const int* ei2 = (const int*)d_in[1];
    const float* feat1 = (const float*)d_in[2];
    const float* feat2 = (const float*)d_in[3];
    const float* avg_v = (const float*)d_in[4];
    const float* W1 = (const float*)d_in[5];
    const float* b1 = (const float*)d_in[6];
    const float* W2 = (const float*)d_in[7];
    const float* b2 = (const float*)d_in[8];
    const float* W3 = (const float*)d_in[9];
    const float* b3 = (const float*)d_in[10];
    const float* Wa = (const float*)d_in[11];
    const float* Wt = (const float*)d_in[12];
    const float* V = (const float*)d_in[13];
    const float* bt = (const float*)d_in[14];
    const float* fc1W = (const float*)d_in[15];
    const float* fc1b = (const float*)d_in[16];
    const float* fc2W = (const float*)d_in[17];
    const float* fc2b = (const float*)d_in[18];
    const float* fc3W = (const float*)d_in[19];
    const float* fc3b = (const float*)d_in[20];
    const float* scW = (const float*)d_in[21];
    const float* scb = (const float*)d_in[22];

    const int E = in_sizes[0] / 2;
    const int N = in_sizes[2] / 64;

    const int nb = N / 128;
    const int nchunk = nb / SIM_CHUNK;
    const int NBLK = nb * nchunk;

    auto layout = [&](int ng, bool commit,
                      float** af, unsigned short** afbf, float** gsum, float** p12,
                      int** cnt, float2** pbmm, unsigned** pbhist,
                      float** dinv, int** offs, int** cursor, int** esrc,
                      float** bufA, float** bufB) -> size_t {
        char* w = (char*)d_ws;
        size_t off = 0;
        auto take = [&](size_t bytes) -> char* {
            char* p = w + off;
            off = (off + bytes + 255) & ~(size_t)255;
            return p;
        };
        char* p;
        p = take((size_t)2 * N * 32 * 4); if (commit) *af = (float*)p;
        p = take((size_t)2 * N * 32 * 2); if (commit) *afbf = (unsigned short*)p;
        p = take((size_t)2 * GS_REP * 32 * GS_PAD * 4); if (commit) *gsum = (float*)p;
        p = take(64 * 4);                 if (commit) *p12 = (float*)p;
        p = take((size_t)ng * N * 4);     if (commit) *cnt = (int*)p;
        p = take((size_t)NBLK * 8);       if (commit) *pbmm = (float2*)p;
        p = take((size_t)NBLK * 16 * 4);  if (commit) *pbhist = (unsigned*)p;
        p = take((size_t)ng * N * 4);     if (commit) *dinv = (float*)p;
        p = take((size_t)ng * (N + 1) * 4); if (commit) *offs = (int*)p;
        p = take((size_t)ng * N * 4);     if (commit) *cursor = (int*)p;
        p = take((size_t)ng * E * 4);     if (commit) *esrc = (int*)p;
        p = take((size_t)ng * N * 128 * 4); if (commit) *bufA = (float*)p;
        p = take((size_t)ng * N * 128 * 4); if (commit) *bufB = (float*)p;
        return off;
    };

    float *af, *gsum, *p12, *dinv, *bufA, *bufB;
    unsigned short* afbf;
    int* cnt;
    float2* pbmm;
    unsigned* pbhist;
    int *offs, *cursor, *esrc;

    size_t need2 = layout(2, false, &af, &afbf, &gsum, &p12, &cnt, &pbmm, &pbhist,
                          &dinv, &offs, &cursor, &esrc, &bufA, &bufB);
    int NG = (ws_size >= need2) ? 2 : 1;
    layout(NG, true, &af, &afbf, &gsum, &p12, &cnt, &pbmm, &pbhist,
           &dinv, &offs, &cursor, &esrc, &bufA, &bufB);

    size_t zbytes = ((char*)cnt + (size_t)NG * N * 4) - (char*)gsum;
    int zn4 = (int)(zbytes / 16);

    // ---- cooperative path availability ----
    int dev = 0;
    hipGetDevice(&dev);
    int coopAttr = 0;
    hipDeviceGetAttribute(&coopAttr, hipDeviceAttributeCooperativeLaunch, dev);
    int nCU = 0;
    hipDeviceGetAttribute(&nCU, hipDeviceAttributeMultiprocessorCount, dev);
    int mab = 0;
    hipError_t occErr = hipOccupancyMaxActiveBlocksPerMultiprocessor(&mab, gnn_coop, 256, 0);
    int G = (occErr == hipSuccess) ? mab * nCU : 0;
    if (G > 1024) G = 1024;

    if (coopAttr && G >= 512 && NG == 2 && G <= NBLK) {
        CoopParams cp;
        cp.ei1 = ei1; cp.ei2 = ei2; cp.x1 = feat1; cp.x2 = feat2;
        cp.W1 = W1; cp.b1 = b1; cp.W2 = W2; cp.b2 = b2; cp.W3 = W3; cp.b3 = b3;
        cp.Wa = Wa; cp.Wt = Wt; cp.V = V; cp.bt = bt;
        cp.fc1W = fc1W; cp.fc1b = fc1b; cp.fc2W = fc2W; cp.fc2b = fc2b;
        cp.fc3W = fc3W; cp.fc3b = fc3b; cp.scW = scW; cp.scb = scb;
        cp.avg_v = avg_v; cp.out = (float*)d_out;
        cp.af = af; cp.afbf = afbf; cp.gsum = gsum; cp.p12 = p12; cp.cnt = cnt;
        cp.pbmm = pbmm; cp.pbhist = pbhist;
        cp.dinv = dinv; cp.offs = offs; cp.cursor = cursor; cp.esrc = esrc;
        cp.bufA = bufA; cp.bufB = bufB;
        cp.zbase = (float4*)gsum; cp.zn4 = zn4;
        cp.N = N; cp.E = E;
        void* args[] = {&cp};
        hipLaunchCooperativeKernel(gnn_coop, dim3(G), dim3(256), args, 0, stream);
        return;
    }

    // ======================= fallback: R8 multi-kernel =======================
    zero_ws<<<(zn4 + 255) / 256, 256, 0, stream>>>((float4*)gsum, zn4);

    int iters = 2 / NG;
    for (int it = 0; it < iters; ++it) {
        const int *srcA, *srcB, *tgtA, *tgtB;
        const float *xA, *xB;
        float* afbase;
        unsigned short* afbfbase;
        float* gsbase;
        if (NG == 2) {
            srcA = ei1; tgtA = ei1 + E; srcB = ei2; tgtB = ei2 + E;
            xA = feat1; xB = feat2;
            afbase = af; afbfbase = afbf; gsbase = gsum;
        } else {
            const int* ei = it ? ei2 : ei1;
            srcA = srcB = ei; tgtA = tgtB = ei + E;
            xA = xB = it ? feat2 : feat1;
            afbase = af + (size_t)it * N * 32;
            afbfbase = afbf + (size_t)it * N * 32;
            gsbase = gsum + (size_t)it * GS_REP * 32 * GS_PAD;
            if (it) {
                int n4 = NG * N * 4 / 16;
                zero_ws<<<(n4 + 255) / 256, 256, 0, stream>>>((float4*)cnt, n4);
            }
        }
        size_t bstride = (size_t)N * 128;

        count_tgt<<<dim3((E + 255) / 256, NG), 256, 0, stream>>>(tgtA, tgtB, cnt, N, E);
        scan_offsets<<<NG, 1024, 0, stream>>>(cnt, offs, cursor, dinv, N);
        scatter_src<<<dim3((E + 255) / 256, NG), 256, 0, stream>>>(srcA, srcB, tgtA, tgtB,
                                                                   cursor, esrc, N, E);
        agg_csr<64, false, false, false><<<dim3(N / 16, NG), 256, 0, stream>>>(
            xA, xB, offs, esrc, dinv, nullptr, bufB, bstride, nullptr, 0, nullptr, N, E);
        tiled_gemm<64, 128, true, true><<<dim3(N / 64, NG), 256, 0, stream>>>(
            bufB, bufB + bstride, W1, b1, bufA, bstride, N);
        tiled_gemm<128, 64, false, false><<<dim3(N / 64, NG), 256, 0, stream>>>(
            bufA, bufA + bstride, W2, nullptr, bufB, bstride, N);
        agg_csr<64, true, false, true><<<dim3(N / 16, NG), 256, 0, stream>>>(
            bufB, bufB + bstride, offs, esrc, dinv, b2, bufA, bstride, nullptr, 0, nullptr,
            N, E);
        tiled_gemm<64, 32, false, false><<<dim3(N / 64, NG), 256, 0, stream>>>(
            bufA, bufA + bstride, W3, nullptr, bufB, bstride, N);
        agg_csr<32, false, true, true><<<dim3(N / 32, NG), 256, 0, stream>>>(
            bufB, bufB + bstride, offs, esrc, dinv, b3, afbase, (size_t)N * 32, afbfbase,
            (size_t)N * 32, gsbase, N, E);
    }

    pool_att<<<dim3(N / 256, 2), 256, 0, stream>>>(af, gsum, Wa, p12, N);
    sim_mfma<false><<<NBLK, 256, 0, stream>>>(afbf, afbf + (size_t)N * 32, N, NBLK, pbmm,
                                              pbhist);
    sim_mfma<true><<<NBLK, 256, 0, stream>>>(afbf, afbf + (size_t)N * 32, N, NBLK, pbmm,
                                             pbhist);
    ntn_final<<<1, 256, 0, stream>>>(p12, Wt, V, bt, pbhist, NBLK, fc1W, fc1b, fc2W, fc2b,
                                     fc3W, fc3b, scW, scb, avg_v, (float*)d_out);
}

// Round 11
// 398.146 us; speedup vs baseline: 2.1560x; 2.1560x over previous
//
#include <hip/hip_runtime.h>
#include <math.h>

// ---------------------------------------------------------------------------
// SimGNN forward on MI355X (gfx950).  R11 = R10 with the agg3_pool af-index
// bug fixed (was writing graph-1 rows out of bounds, trampling afbf).
// Structure: 7 dispatches
//   csr_build (count+scan+scatter+dinv+zero, 2 blocks, counts in LDS)
//   fusedA    (agg1 -> gemm1(+b1,relu) -> gemm2, per 64-row tile)
//   fusedB    (agg2(+b2,relu) -> gemm3)
//   agg3+pool
//   simA      (sim min/max + pool_att merged via blockIdx partition)
//   simB      (sim histogram)
//   ntn_final
// ---------------------------------------------------------------------------

#define SIM_CHUNK 2
#define GS_PAD 16
#define GS_REP 8

using bf16x8 = __attribute__((ext_vector_type(8))) short;
using f32x4  = __attribute__((ext_vector_type(4))) float;

__device__ __forceinline__ unsigned short f2bf(float f) {  // RNE
    unsigned u = __float_as_uint(f);
    unsigned r = ((u >> 16) & 1u) + 0x7FFFu;
    return (unsigned short)((u + r) >> 16);
}

// ---- shared gather helper: dt*(dt_h[r] + sum ds*h[s]) (no bias) ----
template <int F>
__device__ __forceinline__ float4 aggRow(const float* __restrict__ h,
                                         const int* __restrict__ offs,
                                         const int* __restrict__ esrc,
                                         const float* __restrict__ dinv,
                                         int r, int fq) {
    float dt = dinv[r];
    float4 hv = *(const float4*)&h[(size_t)r * F + fq];
    float ax = dt * hv.x, ay = dt * hv.y, az = dt * hv.z, aw = dt * hv.w;
    int e = offs[r], e1 = offs[r + 1];
    for (; e + 4 <= e1; e += 4) {
        int s0 = esrc[e], s1 = esrc[e + 1], s2 = esrc[e + 2], s3 = esrc[e + 3];
        float d0 = dinv[s0], d1 = dinv[s1], d2 = dinv[s2], d3 = dinv[s3];
        float4 v0 = *(const float4*)&h[(size_t)s0 * F + fq];
        float4 v1 = *(const float4*)&h[(size_t)s1 * F + fq];
        float4 v2 = *(const float4*)&h[(size_t)s2 * F + fq];
        float4 v3 = *(const float4*)&h[(size_t)s3 * F + fq];
        ax = fmaf(d0, v0.x, ax); ay = fmaf(d0, v0.y, ay);
        az = fmaf(d0, v0.z, az); aw = fmaf(d0, v0.w, aw);
        ax = fmaf(d1, v1.x, ax); ay = fmaf(d1, v1.y, ay);
        az = fmaf(d1, v1.z, az); aw = fmaf(d1, v1.w, aw);
        ax = fmaf(d2, v2.x, ax); ay = fmaf(d2, v2.y, ay);
        az = fmaf(d2, v2.z, az); aw = fmaf(d2, v2.w, aw);
        ax = fmaf(d3, v3.x, ax); ay = fmaf(d3, v3.y, ay);
        az = fmaf(d3, v3.z, az); aw = fmaf(d3, v3.w, aw);
    }
    for (; e < e1; ++e) {
        int s = esrc[e];
        float ds = dinv[s];
        float4 sv = *(const float4*)&h[(size_t)s * F + fq];
        ax = fmaf(ds, sv.x, ax); ay = fmaf(ds, sv.y, ay);
        az = fmaf(ds, sv.z, az); aw = fmaf(ds, sv.w, aw);
    }
    float4 v;
    v.x = dt * ax; v.y = dt * ay; v.z = dt * az; v.w = dt * aw;
    return v;
}

// ================= csr_build: one block per graph, counts in LDS ===========
__global__ __launch_bounds__(1024) void csr_build(const int* __restrict__ ei1,
                                                  const int* __restrict__ ei2,
                                                  int* __restrict__ offs_,
                                                  int* __restrict__ esrc_,
                                                  float* __restrict__ dinv_,
                                                  float4* __restrict__ zbase, int zn4,
                                                  int N, int E) {
    __shared__ int lcnt[8192];
    __shared__ int lcur[8192];
    __shared__ int wtot[16], wbase[16];
    int g = blockIdx.x;
    int tid = threadIdx.x, lane = tid & 63, wid = tid >> 6;
    const int* ei = g ? ei2 : ei1;
    const int4* t4 = (const int4*)(ei + E);
    const int4* s4 = (const int4*)ei;
    // zero the gsum|p12 accumulator region (split across the 2 blocks)
    for (int i = g * 1024 + tid; i < zn4; i += 2048)
        zbase[i] = make_float4(0.f, 0.f, 0.f, 0.f);
    for (int i = tid; i < N; i += 1024) lcnt[i] = 0;
    __syncthreads();
    // count
    for (int i = tid; i < (E >> 2); i += 1024) {
        int4 v = t4[i];
        atomicAdd(&lcnt[v.x], 1); atomicAdd(&lcnt[v.y], 1);
        atomicAdd(&lcnt[v.z], 1); atomicAdd(&lcnt[v.w], 1);
    }
    __syncthreads();
    // scan (chunk per thread + wave/block scan)
    int chunk = N >> 10;
    int base = tid * chunk;
    int s = 0;
    for (int i = 0; i < chunk; ++i) s += lcnt[base + i];
    int v = s;
#pragma unroll
    for (int d = 1; d < 64; d <<= 1) {
        int u = __shfl_up(v, d);
        if (lane >= d) v += u;
    }
    if (lane == 63) wtot[wid] = v;
    __syncthreads();
    if (tid == 0) {
        int r = 0;
        for (int i = 0; i < 16; ++i) { wbase[i] = r; r += wtot[i]; }
    }
    __syncthreads();
    int run = wbase[wid] + (v - s);
    int* offs = offs_ + g * (N + 1);
    float* dinv = dinv_ + g * N;
    for (int i = 0; i < chunk; ++i) {
        int idx = base + i;
        int c = lcnt[idx];
        offs[idx] = run;
        lcur[idx] = run;
        dinv[idx] = 1.0f / sqrtf((float)(c + 1));
        run += c;
    }
    if (tid == 1023) offs[N] = run;
    __syncthreads();
    // scatter
    int* esrc = esrc_ + (size_t)g * E;
    for (int i = tid; i < (E >> 2); i += 1024) {
        int4 sv = s4[i];
        int4 tv = t4[i];
        int p0 = atomicAdd(&lcur[tv.x], 1); esrc[p0] = sv.x;
        int p1 = atomicAdd(&lcur[tv.y], 1); esrc[p1] = sv.y;
        int p2 = atomicAdd(&lcur[tv.z], 1); esrc[p2] = sv.z;
        int p3 = atomicAdd(&lcur[tv.w], 1); esrc[p3] = sv.w;
    }
}

// ---- generic fallback CSR path (if N not a multiple of 1024 or > 8192) ----
__global__ void zero_ws(float4* __restrict__ p, int n4) {
    int i = blockIdx.x * 256 + threadIdx.x;
    if (i < n4) p[i] = make_float4(0.f, 0.f, 0.f, 0.f);
}
__global__ void count_tgt(const int* __restrict__ t0, const int* __restrict__ t1,
                          int* __restrict__ cnt, int N, int E) {
    int g = blockIdx.y;
    const int* t = g ? t1 : t0;
    int i = blockIdx.x * 256 + threadIdx.x;
    if (i < E) atomicAdd(&cnt[g * N + t[i]], 1);
}
__global__ __launch_bounds__(1024) void scan_offsets(const int* __restrict__ cnt_,
                                                     int* __restrict__ offs_,
                                                     int* __restrict__ cursor_,
                                                     float* __restrict__ dinv_, int N) {
    int g = blockIdx.x;
    const int* cnt = cnt_ + g * N;
    int* offs = offs_ + g * (N + 1);
    int* cursor = cursor_ + g * N;
    float* dinv = dinv_ + g * N;
    int tid = threadIdx.x, lane = tid & 63, wid = tid >> 6;
    int chunk = (N + 1023) >> 10;
    int base = tid * chunk;
    int s = 0;
    for (int i = 0; i < chunk; ++i) {
        int idx = base + i;
        if (idx < N) s += cnt[idx];
    }
    int v = s;
#pragma unroll
    for (int d = 1; d < 64; d <<= 1) {
        int u = __shfl_up(v, d);
        if (lane >= d) v += u;
    }
    __shared__ int wtot[16], wbase[16];
    if (lane == 63) wtot[wid] = v;
    __syncthreads();
    if (tid == 0) {
        int r = 0;
        for (int i = 0; i < 16; ++i) { wbase[i] = r; r += wtot[i]; }
        offs[N] = r;
    }
    __syncthreads();
    int run = wbase[wid] + (v - s);
    for (int i = 0; i < chunk; ++i) {
        int idx = base + i;
        if (idx < N) {
            int c = cnt[idx];
            offs[idx] = run;
            cursor[idx] = run;
            dinv[idx] = 1.0f / sqrtf((float)(c + 1));
            run += c;
        }
    }
}
__global__ void scatter_src(const int* __restrict__ s0, const int* __restrict__ s1,
                            const int* __restrict__ t0, const int* __restrict__ t1,
                            int* __restrict__ cursor, int* __restrict__ esrc, int N, int E) {
    int g = blockIdx.y;
    const int* src = g ? s1 : s0;
    const int* tgt = g ? t1 : t0;
    int i = blockIdx.x * 256 + threadIdx.x;
    if (i < E) {
        int t = tgt[i];
        int pos = atomicAdd(&cursor[g * N + t], 1);
        esrc[g * E + pos] = src[i];
    }
}

// ========= fusedA: agg1(x) -> gemm1(W1,+b1,relu) -> gemm2(W2) -> t1 =========
__global__ __launch_bounds__(256) void fusedA(const float* __restrict__ x1,
                                              const float* __restrict__ x2,
                                              const float* __restrict__ W1,
                                              const float* __restrict__ b1,
                                              const float* __restrict__ W2,
                                              float* __restrict__ t1,
                                              const int* __restrict__ offs_,
                                              const int* __restrict__ esrc_,
                                              const float* __restrict__ dinv_,
                                              int N, int E) {
    __shared__ float X[64][68];
    __shared__ float H1[64][132];
    int g = blockIdx.y;
    const float* x = g ? x2 : x1;
    const int* offs = offs_ + g * (N + 1);
    const int* esrc = esrc_ + (size_t)g * E;
    const float* dinv = dinv_ + g * N;
    int rb = blockIdx.x * 64;
    int tid = threadIdx.x;
    {   // agg1: 16 threads/row, 16 rows/pass, 4 passes
        int fq = (tid & 15) * 4;
        int rl = tid >> 4;
        for (int pass = 0; pass < 4; ++pass) {
            int row = pass * 16 + rl;
            float4 v = aggRow<64>(x, offs, esrc, dinv, rb + row, fq);
            *(float4*)&X[row][fq] = v;
        }
    }
    __syncthreads();
    int tc = tid & 15, tr = tid >> 4;
    {   // gemm1: X(64x64) @ W1(64x128) + b1, relu -> H1
        float acc[4][8];
        float4 b0 = *(const float4*)&b1[tc * 8];
        float4 b4 = *(const float4*)&b1[tc * 8 + 4];
#pragma unroll
        for (int i = 0; i < 4; ++i) {
            acc[i][0] = b0.x; acc[i][1] = b0.y; acc[i][2] = b0.z; acc[i][3] = b0.w;
            acc[i][4] = b4.x; acc[i][5] = b4.y; acc[i][6] = b4.z; acc[i][7] = b4.w;
        }
#pragma unroll 4
        for (int k = 0; k < 64; ++k) {
            float a[4];
#pragma unroll
            for (int i = 0; i < 4; ++i) a[i] = X[tr * 4 + i][k];
            float4 w0 = *(const float4*)&W1[k * 128 + tc * 8];
            float4 w4 = *(const float4*)&W1[k * 128 + tc * 8 + 4];
            float wv[8] = {w0.x, w0.y, w0.z, w0.w, w4.x, w4.y, w4.z, w4.w};
#pragma unroll
            for (int i = 0; i < 4; ++i)
#pragma unroll
                for (int j = 0; j < 8; ++j) acc[i][j] = fmaf(a[i], wv[j], acc[i][j]);
        }
#pragma unroll
        for (int i = 0; i < 4; ++i) {
            float4 o0, o4;
            o0.x = fmaxf(acc[i][0], 0.f); o0.y = fmaxf(acc[i][1], 0.f);
            o0.z = fmaxf(acc[i][2], 0.f); o0.w = fmaxf(acc[i][3], 0.f);
            o4.x = fmaxf(acc[i][4], 0.f); o4.y = fmaxf(acc[i][5], 0.f);
            o4.z = fmaxf(acc[i][6], 0.f); o4.w = fmaxf(acc[i][7], 0.f);
            *(float4*)&H1[tr * 4 + i][tc * 8] = o0;
            *(float4*)&H1[tr * 4 + i][tc * 8 + 4] = o4;
        }
    }
    __syncthreads();
    {   // gemm2: H1(64x128) @ W2(128x64) -> t1
        float acc[4][4];
#pragma unroll
        for (int i = 0; i < 4; ++i)
#pragma unroll
            for (int j = 0; j < 4; ++j) acc[i][j] = 0.f;
#pragma unroll 4
        for (int k = 0; k < 128; ++k) {
            float a[4];
#pragma unroll
            for (int i = 0; i < 4; ++i) a[i] = H1[tr * 4 + i][k];
            float4 w = *(const float4*)&W2[k * 64 + tc * 4];
#pragma unroll
            for (int i = 0; i < 4; ++i) {
                acc[i][0] = fmaf(a[i], w.x, acc[i][0]);
                acc[i][1] = fmaf(a[i], w.y, acc[i][1]);
                acc[i][2] = fmaf(a[i], w.z, acc[i][2]);
                acc[i][3] = fmaf(a[i], w.w, acc[i][3]);
            }
        }
        size_t gbase = (size_t)(g ? N : 0) + rb;
#pragma unroll
        for (int i = 0; i < 4; ++i)
            *(float4*)&t1[(gbase + tr * 4 + i) * 64 + tc * 4] =
                make_float4(acc[i][0], acc[i][1], acc[i][2], acc[i][3]);
    }
}

// ========= fusedB: agg2(t1,+b2,relu) -> gemm3(W3) -> t3 =========
__global__ __launch_bounds__(256) void fusedB(const float* __restrict__ t1,
                                              const float* __restrict__ b2,
                                              const float* __restrict__ W3,
                                              float* __restrict__ t3,
                                              const int* __restrict__ offs_,
                                              const int* __restrict__ esrc_,
                                              const float* __restrict__ dinv_,
                                              int N, int E) {
    __shared__ float X[64][68];
    int g = blockIdx.y;
    const float* h = t1 + (size_t)(g ? N : 0) * 64;
    const int* offs = offs_ + g * (N + 1);
    const int* esrc = esrc_ + (size_t)g * E;
    const float* dinv = dinv_ + g * N;
    int rb = blockIdx.x * 64;
    int tid = threadIdx.x;
    {
        int fq = (tid & 15) * 4;
        int rl = tid >> 4;
        float4 bb = *(const float4*)&b2[fq];
        for (int pass = 0; pass < 4; ++pass) {
            int row = pass * 16 + rl;
            float4 v = aggRow<64>(h, offs, esrc, dinv, rb + row, fq);
            v.x = fmaxf(v.x + bb.x, 0.f); v.y = fmaxf(v.y + bb.y, 0.f);
            v.z = fmaxf(v.z + bb.z, 0.f); v.w = fmaxf(v.w + bb.w, 0.f);
            *(float4*)&X[row][fq] = v;
        }
    }
    __syncthreads();
    int tc = tid & 15, tr = tid >> 4;
    {   // gemm3: X(64x64) @ W3(64x32) -> t3
        float acc[4][2];
#pragma unroll
        for (int i = 0; i < 4; ++i) { acc[i][0] = 0.f; acc[i][1] = 0.f; }
#pragma unroll 4
        for (int k = 0; k < 64; ++k) {
            float a[4];
#pragma unroll
            for (int i = 0; i < 4; ++i) a[i] = X[tr * 4 + i][k];
            float2 w = *(const float2*)&W3[k * 32 + tc * 2];
#pragma unroll
            for (int i = 0; i < 4; ++i) {
                acc[i][0] = fmaf(a[i], w.x, acc[i][0]);
                acc[i][1] = fmaf(a[i], w.y, acc[i][1]);
            }
        }
        size_t gbase = (size_t)(g ? N : 0) + rb;
#pragma unroll
        for (int i = 0; i < 4; ++i)
            *(float2*)&t3[(gbase + tr * 4 + i) * 32 + tc * 2] =
                make_float2(acc[i][0], acc[i][1]);
    }
}

// ========= agg3 + pool (gsum) + bf16 mirror ================================
__global__ __launch_bounds__(256) void agg3_pool(const float* __restrict__ h0,
                                                 const float* __restrict__ h1,
                                                 const int* __restrict__ offs_,
                                                 const int* __restrict__ esrc_,
                                                 const float* __restrict__ dinv_,
                                                 const float* __restrict__ b,
                                                 float* __restrict__ out,
                                                 unsigned short* __restrict__ outbf,
                                                 float* __restrict__ gsum, int N, int E) {
    int g = blockIdx.y;
    const float* h = g ? h1 : h0;
    const int* offs = offs_ + g * (N + 1);
    const int* esrc = esrc_ + (size_t)g * E;
    const float* dinv = dinv_ + g * N;
    int fq = (threadIdx.x & 7) * 4;
    int t = blockIdx.x * 32 + threadIdx.x / 8;
    float4 v = aggRow<32>(h, offs, esrc, dinv, t, fq);
    float4 bb = *(const float4*)&b[fq];
    v.x += bb.x; v.y += bb.y; v.z += bb.z; v.w += bb.w;
    // af laid out [2N][32]  (R10 bug was here: wrote (2N+t) for g=1)
    *(float4*)&out[((size_t)(g * N + t)) * 32 + fq] = v;
    unsigned short r4[4] = {f2bf(v.x), f2bf(v.y), f2bf(v.z), f2bf(v.w)};
    *(uint2*)&outbf[((size_t)(g * N + t)) * 32 + fq] = *(uint2*)r4;
    __shared__ float ls[32];
    if (threadIdx.x < 32) ls[threadIdx.x] = 0.f;
    __syncthreads();
    atomicAdd(&ls[fq + 0], v.x);
    atomicAdd(&ls[fq + 1], v.y);
    atomicAdd(&ls[fq + 2], v.z);
    atomicAdd(&ls[fq + 3], v.w);
    __syncthreads();
    if (threadIdx.x < 32) {
        int rep = blockIdx.x & (GS_REP - 1);
        atomicAdd(&gsum[((g * GS_REP + rep) * 32 + threadIdx.x) * GS_PAD],
                  ls[threadIdx.x]);
    }
}

// ========= simA: sim min/max (blocks < NSIM) + attention pool (rest) ========
__global__ __launch_bounds__(256) void simA(const unsigned short* __restrict__ afbf,
                                            const float* __restrict__ af,
                                            const float* __restrict__ gsum,
                                            const float* __restrict__ Wa,
                                            float* __restrict__ p12,
                                            float2* __restrict__ pbmm, int N, int NSIM) {
    int bid = blockIdx.x;
    int tid = threadIdx.x;
    int lane = tid & 63, wv = tid >> 6;
    if (bid >= NSIM) {
        // ---- attention pool ----
        int pb = bid - NSIM;
        int npg = N / 256;
        int g = pb / npg;
        int r = (pb % npg) * 256 + tid;
        const float* afg = af + (size_t)g * N * 32;
        __shared__ float cm[32], ctxs[32];
        if (tid < 32) {
            float s = 0.f;
#pragma unroll
            for (int rep = 0; rep < GS_REP; ++rep)
                s += gsum[((g * GS_REP + rep) * 32 + tid) * GS_PAD];
            cm[tid] = s / (float)N;
        }
        __syncthreads();
        if (tid < 32) {
            float s = 0.f;
            for (int d = 0; d < 32; ++d) s = fmaf(cm[d], Wa[d * 32 + tid], s);
            ctxs[tid] = tanhf(s);
        }
        __syncthreads();
        float rowv[32];
        const float4* row = (const float4*)(afg + (size_t)r * 32);
        float dot = 0.f;
#pragma unroll
        for (int q = 0; q < 8; ++q) {
            float4 v = row[q];
            rowv[q * 4 + 0] = v.x; rowv[q * 4 + 1] = v.y;
            rowv[q * 4 + 2] = v.z; rowv[q * 4 + 3] = v.w;
            dot = fmaf(v.x, ctxs[q * 4 + 0], dot);
            dot = fmaf(v.y, ctxs[q * 4 + 1], dot);
            dot = fmaf(v.z, ctxs[q * 4 + 2], dot);
            dot = fmaf(v.w, ctxs[q * 4 + 3], dot);
        }
        float att = 1.f / (1.f + expf(-dot));
        __shared__ float wsum[4][32];
#pragma unroll
        for (int f = 0; f < 32; ++f) {
            float v = att * rowv[f];
#pragma unroll
            for (int off = 1; off < 64; off <<= 1) v += __shfl_xor(v, off);
            if (lane == 0) wsum[wv][f] = v;
        }
        __syncthreads();
        if (tid < 32) {
            float s = wsum[0][tid] + wsum[1][tid] + wsum[2][tid] + wsum[3][tid];
            atomicAdd(&p12[g * 32 + tid], s);
        }
        return;
    }
    // ---- sim min/max ----
    const unsigned short* a1 = afbf;
    const unsigned short* a2 = afbf + (size_t)N * 32;
    int nb = N >> 7;
    int nchunk = nb / SIM_CHUNK;
    int by = bid / nchunk;
    int ch = bid % nchunk;
    int r16 = lane & 15, kg = (lane >> 4) << 3;
    const unsigned short* arow = a1 + ((size_t)(by * 128 + (wv >> 1) * 64 + r16)) * 32 + kg;
    bf16x8 afr[4];
#pragma unroll
    for (int m = 0; m < 4; ++m) afr[m] = *(const bf16x8*)(arow + m * 16 * 32);
    float mn = 1e30f, mx = -1e30f;
#pragma unroll
    for (int t = 0; t < SIM_CHUNK; ++t) {
        int bx = ch * SIM_CHUNK + t;
        const unsigned short* brow =
            a2 + ((size_t)(bx * 128 + (wv & 1) * 64 + r16)) * 32 + kg;
        bf16x8 bfr[4];
#pragma unroll
        for (int n = 0; n < 4; ++n) bfr[n] = *(const bf16x8*)(brow + n * 16 * 32);
        f32x4 zero = {0.f, 0.f, 0.f, 0.f};
        f32x4 acc[4][4];
#pragma unroll
        for (int m = 0; m < 4; ++m)
#pragma unroll
            for (int n = 0; n < 4; ++n)
                acc[m][n] =
                    __builtin_amdgcn_mfma_f32_16x16x32_bf16(afr[m], bfr[n], zero, 0, 0, 0);
#pragma unroll
        for (int m = 0; m < 4; ++m)
#pragma unroll
            for (int n = 0; n < 4; ++n)
#pragma unroll
                for (int e = 0; e < 4; ++e) {
                    float v = acc[m][n][e];
                    mn = fminf(mn, v);
                    mx = fmaxf(mx, v);
                }
    }
#pragma unroll
    for (int off = 1; off < 64; off <<= 1) {
        mn = fminf(mn, __shfl_xor(mn, off));
        mx = fmaxf(mx, __shfl_xor(mx, off));
    }
    __shared__ float wmn[4], wmx[4];
    if (lane == 0) { wmn[wv] = mn; wmx[wv] = mx; }
    __syncthreads();
    if (tid == 0) {
        float bmn = fminf(fminf(wmn[0], wmn[1]), fminf(wmn[2], wmn[3]));
        float bmx = fmaxf(fmaxf(wmx[0], wmx[1]), fmaxf(wmx[2], wmx[3]));
        pbmm[bid] = make_float2(bmn, bmx);
    }
}

// ========= simB: histogram (per-block pbmm reduce, packed register bins) ====
__global__ __launch_bounds__(256) void simB(const unsigned short* __restrict__ a1,
                                            const unsigned short* __restrict__ a2,
                                            int N, int nblk,
                                            const float2* __restrict__ pbmm,
                                            unsigned* __restrict__ pbhist) {
    int nb = N >> 7;
    int nchunk = nb / SIM_CHUNK;
    int by = blockIdx.x / nchunk;
    int ch = blockIdx.x % nchunk;
    int w = threadIdx.x >> 6, lane = threadIdx.x & 63;
    int r16 = lane & 15, kg = (lane >> 4) << 3;
    __shared__ unsigned hs[16];
    __shared__ float mnmx[2];
    if (threadIdx.x < 16) hs[threadIdx.x] = 0;
    {
        float mn2 = 1e30f, mx2 = -1e30f;
        for (int i = threadIdx.x; i < nblk; i += 256) {
            float2 vv = pbmm[i];
            mn2 = fminf(mn2, vv.x);
            mx2 = fmaxf(mx2, vv.y);
        }
#pragma unroll
        for (int off = 1; off < 64; off <<= 1) {
            mn2 = fminf(mn2, __shfl_xor(mn2, off));
            mx2 = fmaxf(mx2, __shfl_xor(mx2, off));
        }
        __shared__ float wmn2[4], wmx2[4];
        if (lane == 0) { wmn2[w] = mn2; wmx2[w] = mx2; }
        __syncthreads();
        if (threadIdx.x == 0) {
            mnmx[0] = fminf(fminf(wmn2[0], wmn2[1]), fminf(wmn2[2], wmn2[3]));
            mnmx[1] = fmaxf(fmaxf(wmx2[0], wmx2[1]), fmaxf(wmx2[2], wmx2[3]));
        }
        __syncthreads();
    }
    float mnv = mnmx[0], mxv = mnmx[1];
    float width = (mxv > mnv) ? (mxv - mnv) : 1.0f;
    float scale = 16.0f / width;
    float nbias = -mnv * scale;
    const unsigned short* arow = a1 + ((size_t)(by * 128 + (w >> 1) * 64 + r16)) * 32 + kg;
    bf16x8 afr[4];
#pragma unroll
    for (int m = 0; m < 4; ++m) afr[m] = *(const bf16x8*)(arow + m * 16 * 32);
    unsigned h4_0 = 0, h4_1 = 0, h4_2 = 0, h4_3 = 0;
#pragma unroll
    for (int t = 0; t < SIM_CHUNK; ++t) {
        int bx = ch * SIM_CHUNK + t;
        const unsigned short* brow = a2 + ((size_t)(bx * 128 + (w & 1) * 64 + r16)) * 32 + kg;
        bf16x8 bfr[4];
#pragma unroll
        for (int n = 0; n < 4; ++n) bfr[n] = *(const bf16x8*)(brow + n * 16 * 32);
        f32x4 zero = {0.f, 0.f, 0.f, 0.f};
        f32x4 acc[4][4];
#pragma unroll
        for (int m = 0; m < 4; ++m)
#pragma unroll
            for (int n = 0; n < 4; ++n)
                acc[m][n] =
                    __builtin_amdgcn_mfma_f32_16x16x32_bf16(afr[m], bfr[n], zero, 0, 0, 0);
#pragma unroll
        for (int m = 0; m < 4; ++m)
#pragma unroll
            for (int n = 0; n < 4; ++n)
#pragma unroll
                for (int e = 0; e < 4; ++e) {
                    float v = acc[m][n][e];
                    int bin = (int)fmaf(v, scale, nbias);
                    bin = bin < 0 ? 0 : (bin > 15 ? 15 : bin);
                    unsigned wbit = 1u << ((bin & 3) << 3);
                    int hi = bin >> 2;
                    h4_0 += (hi == 0) ? wbit : 0u;
                    h4_1 += (hi == 1) ? wbit : 0u;
                    h4_2 += (hi == 2) ? wbit : 0u;
                    h4_3 += (hi == 3) ? wbit : 0u;
                }
    }
    unsigned hh[8];
    hh[0] = h4_0 & 0x00FF00FFu; hh[1] = (h4_0 >> 8) & 0x00FF00FFu;
    hh[2] = h4_1 & 0x00FF00FFu; hh[3] = (h4_1 >> 8) & 0x00FF00FFu;
    hh[4] = h4_2 & 0x00FF00FFu; hh[5] = (h4_2 >> 8) & 0x00FF00FFu;
    hh[6] = h4_3 & 0x00FF00FFu; hh[7] = (h4_3 >> 8) & 0x00FF00FFu;
#pragma unroll
    for (int off = 1; off < 64; off <<= 1) {
#pragma unroll
        for (int q = 0; q < 8; ++q) hh[q] += (unsigned)__shfl_xor((int)hh[q], off);
    }
    __syncthreads();
    if (lane < 16) {
        int q = lane >> 2, r = lane & 3;
        unsigned word = hh[2 * q + (r & 1)];
        unsigned val = (r < 2) ? (word & 0xFFFFu) : (word >> 16);
        atomicAdd(&hs[lane], val);
    }
    __syncthreads();
    if (threadIdx.x < 16)
        pbhist[(size_t)blockIdx.x * 16 + threadIdx.x] = hs[threadIdx.x];
}

// ========= hist reduce + NTN + MLP head ====================================
__global__ __launch_bounds__(256) void ntn_final(
    const float* __restrict__ p12, const float* __restrict__ Wt,
    const float* __restrict__ V, const float* __restrict__ bt,
    const unsigned* __restrict__ pbhist, int nblk,
    const float* __restrict__ fc1W, const float* __restrict__ fc1b,
    const float* __restrict__ fc2W, const float* __restrict__ fc2b,
    const float* __restrict__ fc3W, const float* __restrict__ fc3b,
    const float* __restrict__ scW, const float* __restrict__ scb,
    const float* __restrict__ avg_v, float* __restrict__ out) {
    __shared__ float p1l[32], p2l[32];
    __shared__ float scp[16][17];
    __shared__ unsigned hs[16];
    __shared__ float sc[16];
    __shared__ float sfeat[32];
    __shared__ float h1s[16];
    int t = threadIdx.x;
    if (t < 16) hs[t] = 0;
    if (t < 32) p1l[t] = p12[t];
    else if (t < 64) p2l[t - 32] = p12[t];
    __syncthreads();
    {
        const uint4* pb = (const uint4*)pbhist;
        int total = nblk * 4;
        uint4 a = {0u, 0u, 0u, 0u};
        for (int i = t; i < total; i += 256) {
            uint4 v = pb[i];
            a.x += v.x; a.y += v.y; a.z += v.z; a.w += v.w;
        }
#pragma unroll
        for (int off = 4; off < 64; off <<= 1) {
            a.x += (unsigned)__shfl_xor((int)a.x, off);
            a.y += (unsigned)__shfl_xor((int)a.y, off);
            a.z += (unsigned)__shfl_xor((int)a.z, off);
            a.w += (unsigned)__shfl_xor((int)a.w, off);
        }
        int lane = t & 63;
        if (lane < 4) {
            atomicAdd(&hs[lane * 4 + 0], a.x);
            atomicAdd(&hs[lane * 4 + 1], a.y);
            atomicAdd(&hs[lane * 4 + 2], a.z);
            atomicAdd(&hs[lane * 4 + 3], a.w);
        }
    }
    {
        int k = t & 15, dp = t >> 4;
        float s = 0.f;
#pragma unroll
        for (int dd = 0; dd < 2; ++dd) {
            int d = dp * 2 + dd;
            float a = p1l[d];
            for (int e = 0; e < 32; ++e)
                s = fmaf(a * p2l[e], Wt[(d * 32 + e) * 16 + k], s);
        }
        scp[dp][k] = s;
    }
    __syncthreads();
    if (t < 16) {
        float s = 0.f;
#pragma unroll
        for (int dp = 0; dp < 16; ++dp) s += scp[dp][t];
        float bl = 0.f;
        for (int m = 0; m < 32; ++m) bl = fmaf(V[t * 64 + m], p1l[m], bl);
        for (int m = 0; m < 32; ++m) bl = fmaf(V[t * 64 + 32 + m], p2l[m], bl);
        sc[t] = fmaxf(s + bl + bt[t], 0.f);
    }
    __syncthreads();
    if (t < 16) sfeat[t] = sc[t];
    if (t == 16) {
        unsigned tot = 0;
        for (int b = 0; b < 16; ++b) tot += hs[b];
        float ftot = (float)tot;
        for (int b = 0; b < 16; ++b) sfeat[16 + b] = (float)hs[b] / ftot;
    }
    __syncthreads();
    if (t < 16) {
        float a = fc1b[t];
        for (int m = 0; m < 32; ++m) a = fmaf(sfeat[m], fc1W[m * 16 + t], a);
        h1s[t] = fmaxf(a, 0.f);
    }
    __syncthreads();
    if (t != 0) return;
    float h2[8];
    for (int r = 0; r < 8; ++r) {
        float a = fc2b[r];
        for (int m = 0; m < 16; ++m) a = fmaf(h1s[m], fc2W[m * 8 + r], a);
        h2[r] = fmaxf(a, 0.f);
    }
    float h3[4];
    for (int r = 0; r < 4; ++r) {
        float a = fc3b[r];
        for (int m = 0; m < 8; ++m) a = fmaf(h2[m], fc3W[m * 4 + r], a);
        h3[r] = fmaxf(a, 0.f);
    }
    float z = scb[0];
    for (int m = 0; m < 4; ++m) z = fmaf(h3[m], scW[m], z);
    float sig = 1.f / (1.f + expf(-z));
    out[0] = sig;
    out[1] = -logf(sig) * avg_v[0];
}

// ---------------------------------------------------------------------------
extern "C" void kernel_launch(void* const* d_in, const int* in_sizes, int n_in,
                              void* d_out, int out_size, void* d_ws, size_t ws_size,
                              hipStream_t stream) {
    (void)n_in; (void)out_size; (void)ws_size;
    const int* ei1 = (const int*)d_in[0];
    const int* ei2 = (const int*)d_in[1];
    const float* feat1 = (const float*)d_in[2];
    const float* feat2 = (const float*)d_in[3];
    const float* avg_v = (const float*)d_in[4];
    const float* W1 = (const float*)d_in[5];
    const float* b1 = (const float*)d_in[6];
    const float* W2 = (const float*)d_in[7];
    const float* b2 = (const float*)d_in[8];
    const float* W3 = (const float*)d_in[9];
    const float* b3 = (const float*)d_in[10];
    const float* Wa = (const float*)d_in[11];
    const float* Wt = (const float*)d_in[12];
    const float* V = (const float*)d_in[13];
    const float* bt = (const float*)d_in[14];
    const float* fc1W = (const float*)d_in[15];
    const float* fc1b = (const float*)d_in[16];
    const float* fc2W = (const float*)d_in[17];
    const float* fc2b = (const float*)d_in[18];
    const float* fc3W = (const float*)d_in[19];
    const float* fc3b = (const float*)d_in[20];
    const float* scW = (const float*)d_in[21];
    const float* scb = (const float*)d_in[22];

    const int E = in_sizes[0] / 2;
    const int N = in_sizes[2] / 64;
    const int nb = N / 128;
    const int nchunk = nb / SIM_CHUNK;
    const int NSIM = nb * nchunk;

    // ---- workspace layout (gsum|p12 contiguous zero region) ----
    char* w = (char*)d_ws;
    size_t off = 0;
    auto take = [&](size_t bytes) -> char* {
        char* p = w + off;
        off = (off + bytes + 255) & ~(size_t)255;
        return p;
    };
    float* gsum = (float*)take((size_t)2 * GS_REP * 32 * GS_PAD * 4);  // zero start
    float* p12 = (float*)take(64 * 4);                                 // zero end
    float* af = (float*)take((size_t)2 * N * 32 * 4);
    unsigned short* afbf = (unsigned short*)take((size_t)2 * N * 32 * 2);
    float2* pbmm = (float2*)take((size_t)NSIM * 8);
    unsigned* pbhist = (unsigned*)take((size_t)NSIM * 16 * 4);
    float* dinv = (float*)take((size_t)2 * N * 4);
    int* offs = (int*)take((size_t)2 * (N + 1) * 4);
    int* esrc = (int*)take((size_t)2 * E * 4);
    float* t1 = (float*)take((size_t)2 * N * 64 * 4);
    float* t3 = (float*)take((size_t)2 * N * 32 * 4);
    int* cnt = (int*)take((size_t)2 * N * 4);      // fallback path only
    int* cursor = (int*)take((size_t)2 * N * 4);   // fallback path only

    size_t zbytes = ((char*)(p12 + 64)) - (char*)gsum;
    int zn4 = (int)(zbytes / 16);

    if (N <= 8192 && (N % 1024) == 0 && (E % 4) == 0) {
        csr_build<<<2, 1024, 0, stream>>>(ei1, ei2, offs, esrc, dinv, (float4*)gsum,
                                          zn4, N, E);
    } else {
        zero_ws<<<(zn4 + 255) / 256, 256, 0, stream>>>((float4*)gsum, zn4);
        hipMemsetAsync(cnt, 0, (size_t)2 * N * 4, stream);
        count_tgt<<<dim3((E + 255) / 256, 2), 256, 0, stream>>>(ei1 + E, ei2 + E, cnt, N, E);
        scan_offsets<<<2, 1024, 0, stream>>>(cnt, offs, cursor, dinv, N);
        scatter_src<<<dim3((E + 255) / 256, 2), 256, 0, stream>>>(ei1, ei2, ei1 + E,
                                                                  ei2 + E, cursor, esrc,
                                                                  N, E);
    }

    fusedA<<<dim3(N / 64, 2), 256, 0, stream>>>(feat1, feat2, W1, b1, W2, t1, offs, esrc,
                                                dinv, N, E);
    fusedB<<<dim3(N / 64, 2), 256, 0, stream>>>(t1, b2, W3, t3, offs, esrc, dinv, N, E);
    agg3_pool<<<dim3(N / 32, 2), 256, 0, stream>>>(t3, t3 + (size_t)N * 32, offs, esrc,
                                                   dinv, b3, af, afbf, gsum, N, E);
    simA<<<NSIM + (N / 256) * 2, 256, 0, stream>>>(afbf, af, gsum, Wa, p12, pbmm, N, NSIM);
    simB<<<NSIM, 256, 0, stream>>>(afbf, afbf + (size_t)N * 32, N, NSIM, pbmm, pbhist);
    ntn_final<<<1, 256, 0, stream>>>(p12, Wt, V, bt, pbhist, NSIM, fc1W, fc1b, fc2W, fc2b,
                                     fc3W, fc3b, scW, scb, avg_v, (float*)d_out);
}

// Round 12
// 239.333 us; speedup vs baseline: 3.5867x; 1.6636x over previous
//
#include <hip/hip_runtime.h>
#include <math.h>

// ---------------------------------------------------------------------------
// SimGNN forward on MI355X (gfx950).  R12: R11's fused pipeline (proven: all
// post-CSR work = ~68us) + R8's PARALLEL CSR build (R11's 2-block LDS
// csr_build was 330us at 0.27% occupancy -- reverted).
// 10 dispatches:
//   zero_ws | count_tgt | scan_offsets | scatter_src
//   fusedA (agg1->gemm1(+b1,relu)->gemm2) | fusedB (agg2(+b2,relu)->gemm3)
//   agg3+pool | simA (minmax + pool_att) | simB (hist) | ntn_final
// ---------------------------------------------------------------------------

#define SIM_CHUNK 2
#define GS_PAD 16
#define GS_REP 8

using bf16x8 = __attribute__((ext_vector_type(8))) short;
using f32x4  = __attribute__((ext_vector_type(4))) float;

__device__ __forceinline__ unsigned short f2bf(float f) {  // RNE
    unsigned u = __float_as_uint(f);
    unsigned r = ((u >> 16) & 1u) + 0x7FFFu;
    return (unsigned short)((u + r) >> 16);
}

// ---- shared gather helper: dt*(dt*h[r] + sum ds*h[s]) (no bias) ----
template <int F>
__device__ __forceinline__ float4 aggRow(const float* __restrict__ h,
                                         const int* __restrict__ offs,
                                         const int* __restrict__ esrc,
                                         const float* __restrict__ dinv,
                                         int r, int fq) {
    float dt = dinv[r];
    float4 hv = *(const float4*)&h[(size_t)r * F + fq];
    float ax = dt * hv.x, ay = dt * hv.y, az = dt * hv.z, aw = dt * hv.w;
    int e = offs[r], e1 = offs[r + 1];
    for (; e + 4 <= e1; e += 4) {
        int s0 = esrc[e], s1 = esrc[e + 1], s2 = esrc[e + 2], s3 = esrc[e + 3];
        float d0 = dinv[s0], d1 = dinv[s1], d2 = dinv[s2], d3 = dinv[s3];
        float4 v0 = *(const float4*)&h[(size_t)s0 * F + fq];
        float4 v1 = *(const float4*)&h[(size_t)s1 * F + fq];
        float4 v2 = *(const float4*)&h[(size_t)s2 * F + fq];
        float4 v3 = *(const float4*)&h[(size_t)s3 * F + fq];
        ax = fmaf(d0, v0.x, ax); ay = fmaf(d0, v0.y, ay);
        az = fmaf(d0, v0.z, az); aw = fmaf(d0, v0.w, aw);
        ax = fmaf(d1, v1.x, ax); ay = fmaf(d1, v1.y, ay);
        az = fmaf(d1, v1.z, az); aw = fmaf(d1, v1.w, aw);
        ax = fmaf(d2, v2.x, ax); ay = fmaf(d2, v2.y, ay);
        az = fmaf(d2, v2.z, az); aw = fmaf(d2, v2.w, aw);
        ax = fmaf(d3, v3.x, ax); ay = fmaf(d3, v3.y, ay);
        az = fmaf(d3, v3.z, az); aw = fmaf(d3, v3.w, aw);
    }
    for (; e < e1; ++e) {
        int s = esrc[e];
        float ds = dinv[s];
        float4 sv = *(const float4*)&h[(size_t)s * F + fq];
        ax = fmaf(ds, sv.x, ax); ay = fmaf(ds, sv.y, ay);
        az = fmaf(ds, sv.z, az); aw = fmaf(ds, sv.w, aw);
    }
    float4 v;
    v.x = dt * ax; v.y = dt * ay; v.z = dt * az; v.w = dt * aw;
    return v;
}

// ================= parallel CSR build (R8-proven) ===========================
__global__ void zero_ws(float4* __restrict__ p, int n4) {
    int i = blockIdx.x * 256 + threadIdx.x;
    if (i < n4) p[i] = make_float4(0.f, 0.f, 0.f, 0.f);
}

__global__ void count_tgt(const int* __restrict__ t0, const int* __restrict__ t1,
                          int* __restrict__ cnt, int N, int E) {
    int g = blockIdx.y;
    const int* t = g ? t1 : t0;
    int i = blockIdx.x * 256 + threadIdx.x;
    if (i < E) atomicAdd(&cnt[g * N + t[i]], 1);
}

__global__ __launch_bounds__(1024) void scan_offsets(const int* __restrict__ cnt_,
                                                     int* __restrict__ offs_,
                                                     int* __restrict__ cursor_,
                                                     float* __restrict__ dinv_, int N) {
    int g = blockIdx.x;
    const int* cnt = cnt_ + g * N;
    int* offs = offs_ + g * (N + 1);
    int* cursor = cursor_ + g * N;
    float* dinv = dinv_ + g * N;
    int tid = threadIdx.x, lane = tid & 63, wid = tid >> 6;
    int chunk = (N + 1023) >> 10;
    int base = tid * chunk;
    int s = 0;
    for (int i = 0; i < chunk; ++i) {
        int idx = base + i;
        if (idx < N) s += cnt[idx];
    }
    int v = s;
#pragma unroll
    for (int d = 1; d < 64; d <<= 1) {
        int u = __shfl_up(v, d);
        if (lane >= d) v += u;
    }
    __shared__ int wtot[16], wbase[16];
    if (lane == 63) wtot[wid] = v;
    __syncthreads();
    if (tid == 0) {
        int r = 0;
        for (int i = 0; i < 16; ++i) { wbase[i] = r; r += wtot[i]; }
        offs[N] = r;
    }
    __syncthreads();
    int run = wbase[wid] + (v - s);
    for (int i = 0; i < chunk; ++i) {
        int idx = base + i;
        if (idx < N) {
            int c = cnt[idx];
            offs[idx] = run;
            cursor[idx] = run;
            dinv[idx] = 1.0f / sqrtf((float)(c + 1));
            run += c;
        }
    }
}

__global__ void scatter_src(const int* __restrict__ s0, const int* __restrict__ s1,
                            const int* __restrict__ t0, const int* __restrict__ t1,
                            int* __restrict__ cursor, int* __restrict__ esrc, int N, int E) {
    int g = blockIdx.y;
    const int* src = g ? s1 : s0;
    const int* tgt = g ? t1 : t0;
    int i = blockIdx.x * 256 + threadIdx.x;
    if (i < E) {
        int t = tgt[i];
        int pos = atomicAdd(&cursor[g * N + t], 1);
        esrc[g * E + pos] = src[i];
    }
}

// ========= fusedA: agg1(x) -> gemm1(W1,+b1,relu) -> gemm2(W2) -> t1 =========
__global__ __launch_bounds__(256) void fusedA(const float* __restrict__ x1,
                                              const float* __restrict__ x2,
                                              const float* __restrict__ W1,
                                              const float* __restrict__ b1,
                                              const float* __restrict__ W2,
                                              float* __restrict__ t1,
                                              const int* __restrict__ offs_,
                                              const int* __restrict__ esrc_,
                                              const float* __restrict__ dinv_,
                                              int N, int E) {
    __shared__ float X[64][68];
    __shared__ float H1[64][132];
    int g = blockIdx.y;
    const float* x = g ? x2 : x1;
    const int* offs = offs_ + g * (N + 1);
    const int* esrc = esrc_ + (size_t)g * E;
    const float* dinv = dinv_ + g * N;
    int rb = blockIdx.x * 64;
    int tid = threadIdx.x;
    {   // agg1: 16 threads/row, 16 rows/pass, 4 passes
        int fq = (tid & 15) * 4;
        int rl = tid >> 4;
        for (int pass = 0; pass < 4; ++pass) {
            int row = pass * 16 + rl;
            float4 v = aggRow<64>(x, offs, esrc, dinv, rb + row, fq);
            *(float4*)&X[row][fq] = v;
        }
    }
    __syncthreads();
    int tc = tid & 15, tr = tid >> 4;
    {   // gemm1: X(64x64) @ W1(64x128) + b1, relu -> H1
        float acc[4][8];
        float4 b0 = *(const float4*)&b1[tc * 8];
        float4 b4 = *(const float4*)&b1[tc * 8 + 4];
#pragma unroll
        for (int i = 0; i < 4; ++i) {
            acc[i][0] = b0.x; acc[i][1] = b0.y; acc[i][2] = b0.z; acc[i][3] = b0.w;
            acc[i][4] = b4.x; acc[i][5] = b4.y; acc[i][6] = b4.z; acc[i][7] = b4.w;
        }
#pragma unroll 4
        for (int k = 0; k < 64; ++k) {
            float a[4];
#pragma unroll
            for (int i = 0; i < 4; ++i) a[i] = X[tr * 4 + i][k];
            float4 w0 = *(const float4*)&W1[k * 128 + tc * 8];
            float4 w4 = *(const float4*)&W1[k * 128 + tc * 8 + 4];
            float wv[8] = {w0.x, w0.y, w0.z, w0.w, w4.x, w4.y, w4.z, w4.w};
#pragma unroll
            for (int i = 0; i < 4; ++i)
#pragma unroll
                for (int j = 0; j < 8; ++j) acc[i][j] = fmaf(a[i], wv[j], acc[i][j]);
        }
#pragma unroll
        for (int i = 0; i < 4; ++i) {
            float4 o0, o4;
            o0.x = fmaxf(acc[i][0], 0.f); o0.y = fmaxf(acc[i][1], 0.f);
            o0.z = fmaxf(acc[i][2], 0.f); o0.w = fmaxf(acc[i][3], 0.f);
            o4.x = fmaxf(acc[i][4], 0.f); o4.y = fmaxf(acc[i][5], 0.f);
            o4.z = fmaxf(acc[i][6], 0.f); o4.w = fmaxf(acc[i][7], 0.f);
            *(float4*)&H1[tr * 4 + i][tc * 8] = o0;
            *(float4*)&H1[tr * 4 + i][tc * 8 + 4] = o4;
        }
    }
    __syncthreads();
    {   // gemm2: H1(64x128) @ W2(128x64) -> t1
        float acc[4][4];
#pragma unroll
        for (int i = 0; i < 4; ++i)
#pragma unroll
            for (int j = 0; j < 4; ++j) acc[i][j] = 0.f;
#pragma unroll 4
        for (int k = 0; k < 128; ++k) {
            float a[4];
#pragma unroll
            for (int i = 0; i < 4; ++i) a[i] = H1[tr * 4 + i][k];
            float4 w = *(const float4*)&W2[k * 64 + tc * 4];
#pragma unroll
            for (int i = 0; i < 4; ++i) {
                acc[i][0] = fmaf(a[i], w.x, acc[i][0]);
                acc[i][1] = fmaf(a[i], w.y, acc[i][1]);
                acc[i][2] = fmaf(a[i], w.z, acc[i][2]);
                acc[i][3] = fmaf(a[i], w.w, acc[i][3]);
            }
        }
        size_t gbase = (size_t)(g ? N : 0) + rb;
#pragma unroll
        for (int i = 0; i < 4; ++i)
            *(float4*)&t1[(gbase + tr * 4 + i) * 64 + tc * 4] =
                make_float4(acc[i][0], acc[i][1], acc[i][2], acc[i][3]);
    }
}

// ========= fusedB: agg2(t1,+b2,relu) -> gemm3(W3) -> t3 =========
__global__ __launch_bounds__(256) void fusedB(const float* __restrict__ t1,
                                              const float* __restrict__ b2,
                                              const float* __restrict__ W3,
                                              float* __restrict__ t3,
                                              const int* __restrict__ offs_,
                                              const int* __restrict__ esrc_,
                                              const float* __restrict__ dinv_,
                                              int N, int E) {
    __shared__ float X[64][68];
    int g = blockIdx.y;
    const float* h = t1 + (size_t)(g ? N : 0) * 64;
    const int* offs = offs_ + g * (N + 1);
    const int* esrc = esrc_ + (size_t)g * E;
    const float* dinv = dinv_ + g * N;
    int rb = blockIdx.x * 64;
    int tid = threadIdx.x;
    {
        int fq = (tid & 15) * 4;
        int rl = tid >> 4;
        float4 bb = *(const float4*)&b2[fq];
        for (int pass = 0; pass < 4; ++pass) {
            int row = pass * 16 + rl;
            float4 v = aggRow<64>(h, offs, esrc, dinv, rb + row, fq);
            v.x = fmaxf(v.x + bb.x, 0.f); v.y = fmaxf(v.y + bb.y, 0.f);
            v.z = fmaxf(v.z + bb.z, 0.f); v.w = fmaxf(v.w + bb.w, 0.f);
            *(float4*)&X[row][fq] = v;
        }
    }
    __syncthreads();
    int tc = tid & 15, tr = tid >> 4;
    {   // gemm3: X(64x64) @ W3(64x32) -> t3
        float acc[4][2];
#pragma unroll
        for (int i = 0; i < 4; ++i) { acc[i][0] = 0.f; acc[i][1] = 0.f; }
#pragma unroll 4
        for (int k = 0; k < 64; ++k) {
            float a[4];
#pragma unroll
            for (int i = 0; i < 4; ++i) a[i] = X[tr * 4 + i][k];
            float2 w = *(const float2*)&W3[k * 32 + tc * 2];
#pragma unroll
            for (int i = 0; i < 4; ++i) {
                acc[i][0] = fmaf(a[i], w.x, acc[i][0]);
                acc[i][1] = fmaf(a[i], w.y, acc[i][1]);
            }
        }
        size_t gbase = (size_t)(g ? N : 0) + rb;
#pragma unroll
        for (int i = 0; i < 4; ++i)
            *(float2*)&t3[(gbase + tr * 4 + i) * 32 + tc * 2] =
                make_float2(acc[i][0], acc[i][1]);
    }
}

// ========= agg3 + pool (gsum) + bf16 mirror ================================
__global__ __launch_bounds__(256) void agg3_pool(const float* __restrict__ h0,
                                                 const float* __restrict__ h1,
                                                 const int* __restrict__ offs_,
                                                 const int* __restrict__ esrc_,
                                                 const float* __restrict__ dinv_,
                                                 const float* __restrict__ b,
                                                 float* __restrict__ out,
                                                 unsigned short* __restrict__ outbf,
                                                 float* __restrict__ gsum, int N, int E) {
    int g = blockIdx.y;
    const float* h = g ? h1 : h0;
    const int* offs = offs_ + g * (N + 1);
    const int* esrc = esrc_ + (size_t)g * E;
    const float* dinv = dinv_ + g * N;
    int fq = (threadIdx.x & 7) * 4;
    int t = blockIdx.x * 32 + threadIdx.x / 8;
    float4 v = aggRow<32>(h, offs, esrc, dinv, t, fq);
    float4 bb = *(const float4*)&b[fq];
    v.x += bb.x; v.y += bb.y; v.z += bb.z; v.w += bb.w;
    *(float4*)&out[((size_t)(g * N + t)) * 32 + fq] = v;
    unsigned short r4[4] = {f2bf(v.x), f2bf(v.y), f2bf(v.z), f2bf(v.w)};
    *(uint2*)&outbf[((size_t)(g * N + t)) * 32 + fq] = *(uint2*)r4;
    __shared__ float ls[32];
    if (threadIdx.x < 32) ls[threadIdx.x] = 0.f;
    __syncthreads();
    atomicAdd(&ls[fq + 0], v.x);
    atomicAdd(&ls[fq + 1], v.y);
    atomicAdd(&ls[fq + 2], v.z);
    atomicAdd(&ls[fq + 3], v.w);
    __syncthreads();
    if (threadIdx.x < 32) {
        int rep = blockIdx.x & (GS_REP - 1);
        atomicAdd(&gsum[((g * GS_REP + rep) * 32 + threadIdx.x) * GS_PAD],
                  ls[threadIdx.x]);
    }
}

// ========= simA: sim min/max (blocks < NSIM) + attention pool (rest) ========
__global__ __launch_bounds__(256) void simA(const unsigned short* __restrict__ afbf,
                                            const float* __restrict__ af,
                                            const float* __restrict__ gsum,
                                            const float* __restrict__ Wa,
                                            float* __restrict__ p12,
                                            float2* __restrict__ pbmm, int N, int NSIM) {
    int bid = blockIdx.x;
    int tid = threadIdx.x;
    int lane = tid & 63, wv = tid >> 6;
    if (bid >= NSIM) {
        // ---- attention pool ----
        int pb = bid - NSIM;
        int npg = N / 256;
        int g = pb / npg;
        int r = (pb % npg) * 256 + tid;
        const float* afg = af + (size_t)g * N * 32;
        __shared__ float cm[32], ctxs[32];
        if (tid < 32) {
            float s = 0.f;
#pragma unroll
            for (int rep = 0; rep < GS_REP; ++rep)
                s += gsum[((g * GS_REP + rep) * 32 + tid) * GS_PAD];
            cm[tid] = s / (float)N;
        }
        __syncthreads();
        if (tid < 32) {
            float s = 0.f;
            for (int d = 0; d < 32; ++d) s = fmaf(cm[d], Wa[d * 32 + tid], s);
            ctxs[tid] = tanhf(s);
        }
        __syncthreads();
        float rowv[32];
        const float4* row = (const float4*)(afg + (size_t)r * 32);
        float dot = 0.f;
#pragma unroll
        for (int q = 0; q < 8; ++q) {
            float4 v = row[q];
            rowv[q * 4 + 0] = v.x; rowv[q * 4 + 1] = v.y;
            rowv[q * 4 + 2] = v.z; rowv[q * 4 + 3] = v.w;
            dot = fmaf(v.x, ctxs[q * 4 + 0], dot);
            dot = fmaf(v.y, ctxs[q * 4 + 1], dot);
            dot = fmaf(v.z, ctxs[q * 4 + 2], dot);
            dot = fmaf(v.w, ctxs[q * 4 + 3], dot);
        }
        float att = 1.f / (1.f + expf(-dot));
        __shared__ float wsum[4][32];
#pragma unroll
        for (int f = 0; f < 32; ++f) {
            float v = att * rowv[f];
#pragma unroll
            for (int off = 1; off < 64; off <<= 1) v += __shfl_xor(v, off);
            if (lane == 0) wsum[wv][f] = v;
        }
        __syncthreads();
        if (tid < 32) {
            float s = wsum[0][tid] + wsum[1][tid] + wsum[2][tid] + wsum[3][tid];
            atomicAdd(&p12[g * 32 + tid], s);
        }
        return;
    }
    // ---- sim min/max ----
    const unsigned short* a1 = afbf;
    const unsigned short* a2 = afbf + (size_t)N * 32;
    int nb = N >> 7;
    int nchunk = nb / SIM_CHUNK;
    int by = bid / nchunk;
    int ch = bid % nchunk;
    int r16 = lane & 15, kg = (lane >> 4) << 3;
    const unsigned short* arow = a1 + ((size_t)(by * 128 + (wv >> 1) * 64 + r16)) * 32 + kg;
    bf16x8 afr[4];
#pragma unroll
    for (int m = 0; m < 4; ++m) afr[m] = *(const bf16x8*)(arow + m * 16 * 32);
    float mn = 1e30f, mx = -1e30f;
#pragma unroll
    for (int t = 0; t < SIM_CHUNK; ++t) {
        int bx = ch * SIM_CHUNK + t;
        const unsigned short* brow =
            a2 + ((size_t)(bx * 128 + (wv & 1) * 64 + r16)) * 32 + kg;
        bf16x8 bfr[4];
#pragma unroll
        for (int n = 0; n < 4; ++n) bfr[n] = *(const bf16x8*)(brow + n * 16 * 32);
        f32x4 zero = {0.f, 0.f, 0.f, 0.f};
        f32x4 acc[4][4];
#pragma unroll
        for (int m = 0; m < 4; ++m)
#pragma unroll
            for (int n = 0; n < 4; ++n)
                acc[m][n] =
                    __builtin_amdgcn_mfma_f32_16x16x32_bf16(afr[m], bfr[n], zero, 0, 0, 0);
#pragma unroll
        for (int m = 0; m < 4; ++m)
#pragma unroll
            for (int n = 0; n < 4; ++n)
#pragma unroll
                for (int e = 0; e < 4; ++e) {
                    float v = acc[m][n][e];
                    mn = fminf(mn, v);
                    mx = fmaxf(mx, v);
                }
    }
#pragma unroll
    for (int off = 1; off < 64; off <<= 1) {
        mn = fminf(mn, __shfl_xor(mn, off));
        mx = fmaxf(mx, __shfl_xor(mx, off));
    }
    __shared__ float wmn[4], wmx[4];
    if (lane == 0) { wmn[wv] = mn; wmx[wv] = mx; }
    __syncthreads();
    if (tid == 0) {
        float bmn = fminf(fminf(wmn[0], wmn[1]), fminf(wmn[2], wmn[3]));
        float bmx = fmaxf(fmaxf(wmx[0], wmx[1]), fmaxf(wmx[2], wmx[3]));
        pbmm[bid] = make_float2(bmn, bmx);
    }
}

// ========= simB: histogram (per-block pbmm reduce, packed register bins) ====
__global__ __launch_bounds__(256) void simB(const unsigned short* __restrict__ a1,
                                            const unsigned short* __restrict__ a2,
                                            int N, int nblk,
                                            const float2* __restrict__ pbmm,
                                            unsigned* __restrict__ pbhist) {
    int nb = N >> 7;
    int nchunk = nb / SIM_CHUNK;
    int by = blockIdx.x / nchunk;
    int ch = blockIdx.x % nchunk;
    int w = threadIdx.x >> 6, lane = threadIdx.x & 63;
    int r16 = lane & 15, kg = (lane >> 4) << 3;
    __shared__ unsigned hs[16];
    __shared__ float mnmx[2];
    if (threadIdx.x < 16) hs[threadIdx.x] = 0;
    {
        float mn2 = 1e30f, mx2 = -1e30f;
        for (int i = threadIdx.x; i < nblk; i += 256) {
            float2 vv = pbmm[i];
            mn2 = fminf(mn2, vv.x);
            mx2 = fmaxf(mx2, vv.y);
        }
#pragma unroll
        for (int off = 1; off < 64; off <<= 1) {
            mn2 = fminf(mn2, __shfl_xor(mn2, off));
            mx2 = fmaxf(mx2, __shfl_xor(mx2, off));
        }
        __shared__ float wmn2[4], wmx2[4];
        if (lane == 0) { wmn2[w] = mn2; wmx2[w] = mx2; }
        __syncthreads();
        if (threadIdx.x == 0) {
            mnmx[0] = fminf(fminf(wmn2[0], wmn2[1]), fminf(wmn2[2], wmn2[3]));
            mnmx[1] = fmaxf(fmaxf(wmx2[0], wmx2[1]), fmaxf(wmx2[2], wmx2[3]));
        }
        __syncthreads();
    }
    float mnv = mnmx[0], mxv = mnmx[1];
    float width = (mxv > mnv) ? (mxv - mnv) : 1.0f;
    float scale = 16.0f / width;
    float nbias = -mnv * scale;
    const unsigned short* arow = a1 + ((size_t)(by * 128 + (w >> 1) * 64 + r16)) * 32 + kg;
    bf16x8 afr[4];
#pragma unroll
    for (int m = 0; m < 4; ++m) afr[m] = *(const bf16x8*)(arow + m * 16 * 32);
    unsigned h4_0 = 0, h4_1 = 0, h4_2 = 0, h4_3 = 0;
#pragma unroll
    for (int t = 0; t < SIM_CHUNK; ++t) {
        int bx = ch * SIM_CHUNK + t;
        const unsigned short* brow = a2 + ((size_t)(bx * 128 + (w & 1) * 64 + r16)) * 32 + kg;
        bf16x8 bfr[4];
#pragma unroll
        for (int n = 0; n < 4; ++n) bfr[n] = *(const bf16x8*)(brow + n * 16 * 32);
        f32x4 zero = {0.f, 0.f, 0.f, 0.f};
        f32x4 acc[4][4];
#pragma unroll
        for (int m = 0; m < 4; ++m)
#pragma unroll
            for (int n = 0; n < 4; ++n)
                acc[m][n] =
                    __builtin_amdgcn_mfma_f32_16x16x32_bf16(afr[m], bfr[n], zero, 0, 0, 0);
#pragma unroll
        for (int m = 0; m < 4; ++m)
#pragma unroll
            for (int n = 0; n < 4; ++n)
#pragma unroll
                for (int e = 0; e < 4; ++e) {
                    float v = acc[m][n][e];
                    int bin = (int)fmaf(v, scale, nbias);
                    bin = bin < 0 ? 0 : (bin > 15 ? 15 : bin);
                    unsigned wbit = 1u << ((bin & 3) << 3);
                    int hi = bin >> 2;
                    h4_0 += (hi == 0) ? wbit : 0u;
                    h4_1 += (hi == 1) ? wbit : 0u;
                    h4_2 += (hi == 2) ? wbit : 0u;
                    h4_3 += (hi == 3) ? wbit : 0u;
                }
    }
    unsigned hh[8];
    hh[0] = h4_0 & 0x00FF00FFu; hh[1] = (h4_0 >> 8) & 0x00FF00FFu;
    hh[2] = h4_1 & 0x00FF00FFu; hh[3] = (h4_1 >> 8) & 0x00FF00FFu;
    hh[4] = h4_2 & 0x00FF00FFu; hh[5] = (h4_2 >> 8) & 0x00FF00FFu;
    hh[6] = h4_3 & 0x00FF00FFu; hh[7] = (h4_3 >> 8) & 0x00FF00FFu;
#pragma unroll
    for (int off = 1; off < 64; off <<= 1) {
#pragma unroll
        for (int q = 0; q < 8; ++q) hh[q] += (unsigned)__shfl_xor((int)hh[q], off);
    }
    __syncthreads();
    if (lane < 16) {
        int q = lane >> 2, r = lane & 3;
        unsigned word = hh[2 * q + (r & 1)];
        unsigned val = (r < 2) ? (word & 0xFFFFu) : (word >> 16);
        atomicAdd(&hs[lane], val);
    }
    __syncthreads();
    if (threadIdx.x < 16)
        pbhist[(size_t)blockIdx.x * 16 + threadIdx.x] = hs[threadIdx.x];
}

// ========= hist reduce + NTN + MLP head ====================================
__global__ __launch_bounds__(256) void ntn_final(
    const float* __restrict__ p12, const float* __restrict__ Wt,
    const float* __restrict__ V, const float* __restrict__ bt,
    const unsigned* __restrict__ pbhist, int nblk,
    const float* __restrict__ fc1W, const float* __restrict__ fc1b,
    const float* __restrict__ fc2W, const float* __restrict__ fc2b,
    const float* __restrict__ fc3W, const float* __restrict__ fc3b,
    const float* __restrict__ scW, const float* __restrict__ scb,
    const float* __restrict__ avg_v, float* __restrict__ out) {
    __shared__ float p1l[32], p2l[32];
    __shared__ float scp[16][17];
    __shared__ unsigned hs[16];
    __shared__ float sc[16];
    __shared__ float sfeat[32];
    __shared__ float h1s[16];
    int t = threadIdx.x;
    if (t < 16) hs[t] = 0;
    if (t < 32) p1l[t] = p12[t];
    else if (t < 64) p2l[t - 32] = p12[t];
    __syncthreads();
    {
        const uint4* pb = (const uint4*)pbhist;
        int total = nblk * 4;
        uint4 a = {0u, 0u, 0u, 0u};
        for (int i = t; i < total; i += 256) {
            uint4 v = pb[i];
            a.x += v.x; a.y += v.y; a.z += v.z; a.w += v.w;
        }
#pragma unroll
        for (int off = 4; off < 64; off <<= 1) {
            a.x += (unsigned)__shfl_xor((int)a.x, off);
            a.y += (unsigned)__shfl_xor((int)a.y, off);
            a.z += (unsigned)__shfl_xor((int)a.z, off);
            a.w += (unsigned)__shfl_xor((int)a.w, off);
        }
        int lane = t & 63;
        if (lane < 4) {
            atomicAdd(&hs[lane * 4 + 0], a.x);
            atomicAdd(&hs[lane * 4 + 1], a.y);
            atomicAdd(&hs[lane * 4 + 2], a.z);
            atomicAdd(&hs[lane * 4 + 3], a.w);
        }
    }
    {
        int k = t & 15, dp = t >> 4;
        float s = 0.f;
#pragma unroll
        for (int dd = 0; dd < 2; ++dd) {
            int d = dp * 2 + dd;
            float a = p1l[d];
            for (int e = 0; e < 32; ++e)
                s = fmaf(a * p2l[e], Wt[(d * 32 + e) * 16 + k], s);
        }
        scp[dp][k] = s;
    }
    __syncthreads();
    if (t < 16) {
        float s = 0.f;
#pragma unroll
        for (int dp = 0; dp < 16; ++dp) s += scp[dp][t];
        float bl = 0.f;
        for (int m = 0; m < 32; ++m) bl = fmaf(V[t * 64 + m], p1l[m], bl);
        for (int m = 0; m < 32; ++m) bl = fmaf(V[t * 64 + 32 + m], p2l[m], bl);
        sc[t] = fmaxf(s + bl + bt[t], 0.f);
    }
    __syncthreads();
    if (t < 16) sfeat[t] = sc[t];
    if (t == 16) {
        unsigned tot = 0;
        for (int b = 0; b < 16; ++b) tot += hs[b];
        float ftot = (float)tot;
        for (int b = 0; b < 16; ++b) sfeat[16 + b] = (float)hs[b] / ftot;
    }
    __syncthreads();
    if (t < 16) {
        float a = fc1b[t];
        for (int m = 0; m < 32; ++m) a = fmaf(sfeat[m], fc1W[m * 16 + t], a);
        h1s[t] = fmaxf(a, 0.f);
    }
    __syncthreads();
    if (t != 0) return;
    float h2[8];
    for (int r = 0; r < 8; ++r) {
        float a = fc2b[r];
        for (int m = 0; m < 16; ++m) a = fmaf(h1s[m], fc2W[m * 8 + r], a);
        h2[r] = fmaxf(a, 0.f);
    }
    float h3[4];
    for (int r = 0; r < 4; ++r) {
        float a = fc3b[r];
        for (int m = 0; m < 8; ++m) a = fmaf(h2[m], fc3W[m * 4 + r], a);
        h3[r] = fmaxf(a, 0.f);
    }
    float z = scb[0];
    for (int m = 0; m < 4; ++m) z = fmaf(h3[m], scW[m], z);
    float sig = 1.f / (1.f + expf(-z));
    out[0] = sig;
    out[1] = -logf(sig) * avg_v[0];
}

// ---------------------------------------------------------------------------
extern "C" void kernel_launch(void* const* d_in, const int* in_sizes, int n_in,
                              void* d_out, int out_size, void* d_ws, size_t ws_size,
                              hipStream_t stream) {
    (void)n_in; (void)out_size; (void)ws_size;
    const int* ei1 = (const int*)d_in[0];
    const int* ei2 = (const int*)d_in[1];
    const float* feat1 = (const float*)d_in[2];
    const float* feat2 = (const float*)d_in[3];
    const float* avg_v = (const float*)d_in[4];
    const float* W1 = (const float*)d_in[5];
    const float* b1 = (const float*)d_in[6];
    const float* W2 = (const float*)d_in[7];
    const float* b2 = (const float*)d_in[8];
    const float* W3 = (const float*)d_in[9];
    const float* b3 = (const float*)d_in[10];
    const float* Wa = (const float*)d_in[11];
    const float* Wt = (const float*)d_in[12];
    const float* V = (const float*)d_in[13];
    const float* bt = (const float*)d_in[14];
    const float* fc1W = (const float*)d_in[15];
    const float* fc1b = (const float*)d_in[16];
    const float* fc2W = (const float*)d_in[17];
    const float* fc2b = (const float*)d_in[18];
    const float* fc3W = (const float*)d_in[19];
    const float* fc3b = (const float*)d_in[20];
    const float* scW = (const float*)d_in[21];
    const float* scb = (const float*)d_in[22];

    const int E = in_sizes[0] / 2;
    const int N = in_sizes[2] / 64;
    const int nb = N / 128;
    const int nchunk = nb / SIM_CHUNK;
    const int NSIM = nb * nchunk;

    // ---- workspace layout: gsum | p12 | cnt contiguous => single zero pass ----
    char* w = (char*)d_ws;
    size_t off = 0;
    auto take = [&](size_t bytes) -> char* {
        char* p = w + off;
        off = (off + bytes + 255) & ~(size_t)255;
        return p;
    };
    float* gsum = (float*)take((size_t)2 * GS_REP * 32 * GS_PAD * 4);  // zero start
    float* p12 = (float*)take(64 * 4);
    int* cnt = (int*)take((size_t)2 * N * 4);                          // zero end
    float* af = (float*)take((size_t)2 * N * 32 * 4);
    unsigned short* afbf = (unsigned short*)take((size_t)2 * N * 32 * 2);
    float2* pbmm = (float2*)take((size_t)NSIM * 8);
    unsigned* pbhist = (unsigned*)take((size_t)NSIM * 16 * 4);
    float* dinv = (float*)take((size_t)2 * N * 4);
    int* offs = (int*)take((size_t)2 * (N + 1) * 4);
    int* cursor = (int*)take((size_t)2 * N * 4);
    int* esrc = (int*)take((size_t)2 * E * 4);
    float* t1 = (float*)take((size_t)2 * N * 64 * 4);
    float* t3 = (float*)take((size_t)2 * N * 32 * 4);

    size_t zbytes = ((char*)cnt + (size_t)2 * N * 4) - (char*)gsum;
    int zn4 = (int)(zbytes / 16);

    // ---- parallel CSR build (R8-proven) ----
    zero_ws<<<(zn4 + 255) / 256, 256, 0, stream>>>((float4*)gsum, zn4);
    count_tgt<<<dim3((E + 255) / 256, 2), 256, 0, stream>>>(ei1 + E, ei2 + E, cnt, N, E);
    scan_offsets<<<2, 1024, 0, stream>>>(cnt, offs, cursor, dinv, N);
    scatter_src<<<dim3((E + 255) / 256, 2), 256, 0, stream>>>(ei1, ei2, ei1 + E, ei2 + E,
                                                              cursor, esrc, N, E);

    // ---- fused GCN pipeline (R11-proven) ----
    fusedA<<<dim3(N / 64, 2), 256, 0, stream>>>(feat1, feat2, W1, b1, W2, t1, offs, esrc,
                                                dinv, N, E);
    fusedB<<<dim3(N / 64, 2), 256, 0, stream>>>(t1, b2, W3, t3, offs, esrc, dinv, N, E);
    agg3_pool<<<dim3(N / 32, 2), 256, 0, stream>>>(t3, t3 + (size_t)N * 32, offs, esrc,
                                                   dinv, b3, af, afbf, gsum, N, E);
    simA<<<NSIM + (N / 256) * 2, 256, 0, stream>>>(afbf, af, gsum, Wa, p12, pbmm, N, NSIM);
    simB<<<NSIM, 256, 0, stream>>>(afbf, afbf + (size_t)N * 32, N, NSIM, pbmm, pbhist);
    ntn_final<<<1, 256, 0, stream>>>(p12, Wt, V, bt, pbhist, NSIM, fc1W, fc1b, fc2W, fc2b,
                                     fc3W, fc3b, scW, scb, avg_v, (float*)d_out);
}

// Round 13
// 230.600 us; speedup vs baseline: 3.7225x; 1.0379x over previous
//
#include <hip/hip_runtime.h>
#include <math.h>

// ---------------------------------------------------------------------------
// SimGNN forward on MI355X (gfx950).  R13 = R12 with fusedA/fusedB re-tiled
// from 64-row to 16-row blocks (R12: 256 blocks = 1/CU = 4 waves -> 10% occ,
// latency-bound gather at 47us).  Now 1024 blocks = 4/CU = 16 waves/CU.
// ---------------------------------------------------------------------------

#define SIM_CHUNK 2
#define GS_PAD 16
#define GS_REP 8

using bf16x8 = __attribute__((ext_vector_type(8))) short;
using f32x4  = __attribute__((ext_vector_type(4))) float;

__device__ __forceinline__ unsigned short f2bf(float f) {  // RNE
    unsigned u = __float_as_uint(f);
    unsigned r = ((u >> 16) & 1u) + 0x7FFFu;
    return (unsigned short)((u + r) >> 16);
}

// ---- shared gather helper: dt*(dt*h[r] + sum ds*h[s]) (no bias) ----
template <int F>
__device__ __forceinline__ float4 aggRow(const float* __restrict__ h,
                                         const int* __restrict__ offs,
                                         const int* __restrict__ esrc,
                                         const float* __restrict__ dinv,
                                         int r, int fq) {
    float dt = dinv[r];
    float4 hv = *(const float4*)&h[(size_t)r * F + fq];
    float ax = dt * hv.x, ay = dt * hv.y, az = dt * hv.z, aw = dt * hv.w;
    int e = offs[r], e1 = offs[r + 1];
    for (; e + 4 <= e1; e += 4) {
        int s0 = esrc[e], s1 = esrc[e + 1], s2 = esrc[e + 2], s3 = esrc[e + 3];
        float d0 = dinv[s0], d1 = dinv[s1], d2 = dinv[s2], d3 = dinv[s3];
        float4 v0 = *(const float4*)&h[(size_t)s0 * F + fq];
        float4 v1 = *(const float4*)&h[(size_t)s1 * F + fq];
        float4 v2 = *(const float4*)&h[(size_t)s2 * F + fq];
        float4 v3 = *(const float4*)&h[(size_t)s3 * F + fq];
        ax = fmaf(d0, v0.x, ax); ay = fmaf(d0, v0.y, ay);
        az = fmaf(d0, v0.z, az); aw = fmaf(d0, v0.w, aw);
        ax = fmaf(d1, v1.x, ax); ay = fmaf(d1, v1.y, ay);
        az = fmaf(d1, v1.z, az); aw = fmaf(d1, v1.w, aw);
        ax = fmaf(d2, v2.x, ax); ay = fmaf(d2, v2.y, ay);
        az = fmaf(d2, v2.z, az); aw = fmaf(d2, v2.w, aw);
        ax = fmaf(d3, v3.x, ax); ay = fmaf(d3, v3.y, ay);
        az = fmaf(d3, v3.z, az); aw = fmaf(d3, v3.w, aw);
    }
    for (; e < e1; ++e) {
        int s = esrc[e];
        float ds = dinv[s];
        float4 sv = *(const float4*)&h[(size_t)s * F + fq];
        ax = fmaf(ds, sv.x, ax); ay = fmaf(ds, sv.y, ay);
        az = fmaf(ds, sv.z, az); aw = fmaf(ds, sv.w, aw);
    }
    float4 v;
    v.x = dt * ax; v.y = dt * ay; v.z = dt * az; v.w = dt * aw;
    return v;
}

// ================= parallel CSR build (R8-proven) ===========================
__global__ void zero_ws(float4* __restrict__ p, int n4) {
    int i = blockIdx.x * 256 + threadIdx.x;
    if (i < n4) p[i] = make_float4(0.f, 0.f, 0.f, 0.f);
}

__global__ void count_tgt(const int* __restrict__ t0, const int* __restrict__ t1,
                          int* __restrict__ cnt, int N, int E) {
    int g = blockIdx.y;
    const int* t = g ? t1 : t0;
    int i = blockIdx.x * 256 + threadIdx.x;
    if (i < E) atomicAdd(&cnt[g * N + t[i]], 1);
}

__global__ __launch_bounds__(1024) void scan_offsets(const int* __restrict__ cnt_,
                                                     int* __restrict__ offs_,
                                                     int* __restrict__ cursor_,
                                                     float* __restrict__ dinv_, int N) {
    int g = blockIdx.x;
    const int* cnt = cnt_ + g * N;
    int* offs = offs_ + g * (N + 1);
    int* cursor = cursor_ + g * N;
    float* dinv = dinv_ + g * N;
    int tid = threadIdx.x, lane = tid & 63, wid = tid >> 6;
    int chunk = (N + 1023) >> 10;
    int base = tid * chunk;
    int s = 0;
    for (int i = 0; i < chunk; ++i) {
        int idx = base + i;
        if (idx < N) s += cnt[idx];
    }
    int v = s;
#pragma unroll
    for (int d = 1; d < 64; d <<= 1) {
        int u = __shfl_up(v, d);
        if (lane >= d) v += u;
    }
    __shared__ int wtot[16], wbase[16];
    if (lane == 63) wtot[wid] = v;
    __syncthreads();
    if (tid == 0) {
        int r = 0;
        for (int i = 0; i < 16; ++i) { wbase[i] = r; r += wtot[i]; }
        offs[N] = r;
    }
    __syncthreads();
    int run = wbase[wid] + (v - s);
    for (int i = 0; i < chunk; ++i) {
        int idx = base + i;
        if (idx < N) {
            int c = cnt[idx];
            offs[idx] = run;
            cursor[idx] = run;
            dinv[idx] = 1.0f / sqrtf((float)(c + 1));
            run += c;
        }
    }
}

__global__ void scatter_src(const int* __restrict__ s0, const int* __restrict__ s1,
                            const int* __restrict__ t0, const int* __restrict__ t1,
                            int* __restrict__ cursor, int* __restrict__ esrc, int N, int E) {
    int g = blockIdx.y;
    const int* src = g ? s1 : s0;
    const int* tgt = g ? t1 : t0;
    int i = blockIdx.x * 256 + threadIdx.x;
    if (i < E) {
        int t = tgt[i];
        int pos = atomicAdd(&cursor[g * N + t], 1);
        esrc[g * E + pos] = src[i];
    }
}

// ========= fusedA: agg1(x) -> gemm1(W1,+b1,relu) -> gemm2(W2) -> t1 =========
// 16-row tile, 256 threads, 4 blocks/CU.
__global__ __launch_bounds__(256) void fusedA(const float* __restrict__ x1,
                                              const float* __restrict__ x2,
                                              const float* __restrict__ W1,
                                              const float* __restrict__ b1,
                                              const float* __restrict__ W2,
                                              float* __restrict__ t1,
                                              const int* __restrict__ offs_,
                                              const int* __restrict__ esrc_,
                                              const float* __restrict__ dinv_,
                                              int N, int E) {
    __shared__ float X[16][68];
    __shared__ float H1[16][132];
    int g = blockIdx.y;
    const float* x = g ? x2 : x1;
    const int* offs = offs_ + g * (N + 1);
    const int* esrc = esrc_ + (size_t)g * E;
    const float* dinv = dinv_ + g * N;
    int rb = blockIdx.x * 16;
    int tid = threadIdx.x;
    int tc = tid & 15, tr = tid >> 4;  // 16x16
    {   // agg1: 16 threads/row, all 16 rows in one pass
        int fq = tc * 4;
        float4 v = aggRow<64>(x, offs, esrc, dinv, rb + tr, fq);
        *(float4*)&X[tr][fq] = v;
    }
    __syncthreads();
    {   // gemm1: X(16x64) @ W1(64x128) + b1, relu -> H1; thread = (row tr, 8 cols)
        float acc[8];
        float4 b0 = *(const float4*)&b1[tc * 8];
        float4 b4 = *(const float4*)&b1[tc * 8 + 4];
        acc[0] = b0.x; acc[1] = b0.y; acc[2] = b0.z; acc[3] = b0.w;
        acc[4] = b4.x; acc[5] = b4.y; acc[6] = b4.z; acc[7] = b4.w;
#pragma unroll 8
        for (int k = 0; k < 64; ++k) {
            float a = X[tr][k];
            float4 w0 = *(const float4*)&W1[k * 128 + tc * 8];
            float4 w4 = *(const float4*)&W1[k * 128 + tc * 8 + 4];
            acc[0] = fmaf(a, w0.x, acc[0]); acc[1] = fmaf(a, w0.y, acc[1]);
            acc[2] = fmaf(a, w0.z, acc[2]); acc[3] = fmaf(a, w0.w, acc[3]);
            acc[4] = fmaf(a, w4.x, acc[4]); acc[5] = fmaf(a, w4.y, acc[5]);
            acc[6] = fmaf(a, w4.z, acc[6]); acc[7] = fmaf(a, w4.w, acc[7]);
        }
        float4 o0, o4;
        o0.x = fmaxf(acc[0], 0.f); o0.y = fmaxf(acc[1], 0.f);
        o0.z = fmaxf(acc[2], 0.f); o0.w = fmaxf(acc[3], 0.f);
        o4.x = fmaxf(acc[4], 0.f); o4.y = fmaxf(acc[5], 0.f);
        o4.z = fmaxf(acc[6], 0.f); o4.w = fmaxf(acc[7], 0.f);
        *(float4*)&H1[tr][tc * 8] = o0;
        *(float4*)&H1[tr][tc * 8 + 4] = o4;
    }
    __syncthreads();
    {   // gemm2: H1(16x128) @ W2(128x64) -> t1; thread = (row tr, 4 cols)
        float acc[4] = {0.f, 0.f, 0.f, 0.f};
#pragma unroll 8
        for (int k = 0; k < 128; ++k) {
            float a = H1[tr][k];
            float4 w = *(const float4*)&W2[k * 64 + tc * 4];
            acc[0] = fmaf(a, w.x, acc[0]);
            acc[1] = fmaf(a, w.y, acc[1]);
            acc[2] = fmaf(a, w.z, acc[2]);
            acc[3] = fmaf(a, w.w, acc[3]);
        }
        size_t row = (size_t)(g ? N : 0) + rb + tr;
        *(float4*)&t1[row * 64 + tc * 4] = make_float4(acc[0], acc[1], acc[2], acc[3]);
    }
}

// ========= fusedB: agg2(t1,+b2,relu) -> gemm3(W3) -> t3 =========
// 16-row tile, 256 threads.
__global__ __launch_bounds__(256) void fusedB(const float* __restrict__ t1,
                                              const float* __restrict__ b2,
                                              const float* __restrict__ W3,
                                              float* __restrict__ t3,
                                              const int* __restrict__ offs_,
                                              const int* __restrict__ esrc_,
                                              const float* __restrict__ dinv_,
                                              int N, int E) {
    __shared__ float X[16][68];
    int g = blockIdx.y;
    const float* h = t1 + (size_t)(g ? N : 0) * 64;
    const int* offs = offs_ + g * (N + 1);
    const int* esrc = esrc_ + (size_t)g * E;
    const float* dinv = dinv_ + g * N;
    int rb = blockIdx.x * 16;
    int tid = threadIdx.x;
    int tc = tid & 15, tr = tid >> 4;
    {
        int fq = tc * 4;
        float4 bb = *(const float4*)&b2[fq];
        float4 v = aggRow<64>(h, offs, esrc, dinv, rb + tr, fq);
        v.x = fmaxf(v.x + bb.x, 0.f); v.y = fmaxf(v.y + bb.y, 0.f);
        v.z = fmaxf(v.z + bb.z, 0.f); v.w = fmaxf(v.w + bb.w, 0.f);
        *(float4*)&X[tr][fq] = v;
    }
    __syncthreads();
    {   // gemm3: X(16x64) @ W3(64x32) -> t3; thread = (row tr, 2 cols)
        float acc[2] = {0.f, 0.f};
#pragma unroll 8
        for (int k = 0; k < 64; ++k) {
            float a = X[tr][k];
            float2 w = *(const float2*)&W3[k * 32 + tc * 2];
            acc[0] = fmaf(a, w.x, acc[0]);
            acc[1] = fmaf(a, w.y, acc[1]);
        }
        size_t row = (size_t)(g ? N : 0) + rb + tr;
        *(float2*)&t3[row * 32 + tc * 2] = make_float2(acc[0], acc[1]);
    }
}

// ========= agg3 + pool (gsum) + bf16 mirror ================================
__global__ __launch_bounds__(256) void agg3_pool(const float* __restrict__ h0,
                                                 const float* __restrict__ h1,
                                                 const int* __restrict__ offs_,
                                                 const int* __restrict__ esrc_,
                                                 const float* __restrict__ dinv_,
                                                 const float* __restrict__ b,
                                                 float* __restrict__ out,
                                                 unsigned short* __restrict__ outbf,
                                                 float* __restrict__ gsum, int N, int E) {
    int g = blockIdx.y;
    const float* h = g ? h1 : h0;
    const int* offs = offs_ + g * (N + 1);
    const int* esrc = esrc_ + (size_t)g * E;
    const float* dinv = dinv_ + g * N;
    int fq = (threadIdx.x & 7) * 4;
    int t = blockIdx.x * 32 + threadIdx.x / 8;
    float4 v = aggRow<32>(h, offs, esrc, dinv, t, fq);
    float4 bb = *(const float4*)&b[fq];
    v.x += bb.x; v.y += bb.y; v.z += bb.z; v.w += bb.w;
    *(float4*)&out[((size_t)(g * N + t)) * 32 + fq] = v;
    unsigned short r4[4] = {f2bf(v.x), f2bf(v.y), f2bf(v.z), f2bf(v.w)};
    *(uint2*)&outbf[((size_t)(g * N + t)) * 32 + fq] = *(uint2*)r4;
    __shared__ float ls[32];
    if (threadIdx.x < 32) ls[threadIdx.x] = 0.f;
    __syncthreads();
    atomicAdd(&ls[fq + 0], v.x);
    atomicAdd(&ls[fq + 1], v.y);
    atomicAdd(&ls[fq + 2], v.z);
    atomicAdd(&ls[fq + 3], v.w);
    __syncthreads();
    if (threadIdx.x < 32) {
        int rep = blockIdx.x & (GS_REP - 1);
        atomicAdd(&gsum[((g * GS_REP + rep) * 32 + threadIdx.x) * GS_PAD],
                  ls[threadIdx.x]);
    }
}

// ========= simA: sim min/max (blocks < NSIM) + attention pool (rest) ========
__global__ __launch_bounds__(256) void simA(const unsigned short* __restrict__ afbf,
                                            const float* __restrict__ af,
                                            const float* __restrict__ gsum,
                                            const float* __restrict__ Wa,
                                            float* __restrict__ p12,
                                            float2* __restrict__ pbmm, int N, int NSIM) {
    int bid = blockIdx.x;
    int tid = threadIdx.x;
    int lane = tid & 63, wv = tid >> 6;
    if (bid >= NSIM) {
        // ---- attention pool ----
        int pb = bid - NSIM;
        int npg = N / 256;
        int g = pb / npg;
        int r = (pb % npg) * 256 + tid;
        const float* afg = af + (size_t)g * N * 32;
        __shared__ float cm[32], ctxs[32];
        if (tid < 32) {
            float s = 0.f;
#pragma unroll
            for (int rep = 0; rep < GS_REP; ++rep)
                s += gsum[((g * GS_REP + rep) * 32 + tid) * GS_PAD];
            cm[tid] = s / (float)N;
        }
        __syncthreads();
        if (tid < 32) {
            float s = 0.f;
            for (int d = 0; d < 32; ++d) s = fmaf(cm[d], Wa[d * 32 + tid], s);
            ctxs[tid] = tanhf(s);
        }
        __syncthreads();
        float rowv[32];
        const float4* row = (const float4*)(afg + (size_t)r * 32);
        float dot = 0.f;
#pragma unroll
        for (int q = 0; q < 8; ++q) {
            float4 v = row[q];
            rowv[q * 4 + 0] = v.x; rowv[q * 4 + 1] = v.y;
            rowv[q * 4 + 2] = v.z; rowv[q * 4 + 3] = v.w;
            dot = fmaf(v.x, ctxs[q * 4 + 0], dot);
            dot = fmaf(v.y, ctxs[q * 4 + 1], dot);
            dot = fmaf(v.z, ctxs[q * 4 + 2], dot);
            dot = fmaf(v.w, ctxs[q * 4 + 3], dot);
        }
        float att = 1.f / (1.f + expf(-dot));
        __shared__ float wsum[4][32];
#pragma unroll
        for (int f = 0; f < 32; ++f) {
            float v = att * rowv[f];
#pragma unroll
            for (int off = 1; off < 64; off <<= 1) v += __shfl_xor(v, off);
            if (lane == 0) wsum[wv][f] = v;
        }
        __syncthreads();
        if (tid < 32) {
            float s = wsum[0][tid] + wsum[1][tid] + wsum[2][tid] + wsum[3][tid];
            atomicAdd(&p12[g * 32 + tid], s);
        }
        return;
    }
    // ---- sim min/max ----
    const unsigned short* a1 = afbf;
    const unsigned short* a2 = afbf + (size_t)N * 32;
    int nb = N >> 7;
    int nchunk = nb / SIM_CHUNK;
    int by = bid / nchunk;
    int ch = bid % nchunk;
    int r16 = lane & 15, kg = (lane >> 4) << 3;
    const unsigned short* arow = a1 + ((size_t)(by * 128 + (wv >> 1) * 64 + r16)) * 32 + kg;
    bf16x8 afr[4];
#pragma unroll
    for (int m = 0; m < 4; ++m) afr[m] = *(const bf16x8*)(arow + m * 16 * 32);
    float mn = 1e30f, mx = -1e30f;
#pragma unroll
    for (int t = 0; t < SIM_CHUNK; ++t) {
        int bx = ch * SIM_CHUNK + t;
        const unsigned short* brow =
            a2 + ((size_t)(bx * 128 + (wv & 1) * 64 + r16)) * 32 + kg;
        bf16x8 bfr[4];
#pragma unroll
        for (int n = 0; n < 4; ++n) bfr[n] = *(const bf16x8*)(brow + n * 16 * 32);
        f32x4 zero = {0.f, 0.f, 0.f, 0.f};
        f32x4 acc[4][4];
#pragma unroll
        for (int m = 0; m < 4; ++m)
#pragma unroll
            for (int n = 0; n < 4; ++n)
                acc[m][n] =
                    __builtin_amdgcn_mfma_f32_16x16x32_bf16(afr[m], bfr[n], zero, 0, 0, 0);
#pragma unroll
        for (int m = 0; m < 4; ++m)
#pragma unroll
            for (int n = 0; n < 4; ++n)
#pragma unroll
                for (int e = 0; e < 4; ++e) {
                    float v = acc[m][n][e];
                    mn = fminf(mn, v);
                    mx = fmaxf(mx, v);
                }
    }
#pragma unroll
    for (int off = 1; off < 64; off <<= 1) {
        mn = fminf(mn, __shfl_xor(mn, off));
        mx = fmaxf(mx, __shfl_xor(mx, off));
    }
    __shared__ float wmn[4], wmx[4];
    if (lane == 0) { wmn[wv] = mn; wmx[wv] = mx; }
    __syncthreads();
    if (tid == 0) {
        float bmn = fminf(fminf(wmn[0], wmn[1]), fminf(wmn[2], wmn[3]));
        float bmx = fmaxf(fmaxf(wmx[0], wmx[1]), fmaxf(wmx[2], wmx[3]));
        pbmm[bid] = make_float2(bmn, bmx);
    }
}

// ========= simB: histogram (per-block pbmm reduce, packed register bins) ====
__global__ __launch_bounds__(256) void simB(const unsigned short* __restrict__ a1,
                                            const unsigned short* __restrict__ a2,
                                            int N, int nblk,
                                            const float2* __restrict__ pbmm,
                                            unsigned* __restrict__ pbhist) {
    int nb = N >> 7;
    int nchunk = nb / SIM_CHUNK;
    int by = blockIdx.x / nchunk;
    int ch = blockIdx.x % nchunk;
    int w = threadIdx.x >> 6, lane = threadIdx.x & 63;
    int r16 = lane & 15, kg = (lane >> 4) << 3;
    __shared__ unsigned hs[16];
    __shared__ float mnmx[2];
    if (threadIdx.x < 16) hs[threadIdx.x] = 0;
    {
        float mn2 = 1e30f, mx2 = -1e30f;
        for (int i = threadIdx.x; i < nblk; i += 256) {
            float2 vv = pbmm[i];
            mn2 = fminf(mn2, vv.x);
            mx2 = fmaxf(mx2, vv.y);
        }
#pragma unroll
        for (int off = 1; off < 64; off <<= 1) {
            mn2 = fminf(mn2, __shfl_xor(mn2, off));
            mx2 = fmaxf(mx2, __shfl_xor(mx2, off));
        }
        __shared__ float wmn2[4], wmx2[4];
        if (lane == 0) { wmn2[w] = mn2; wmx2[w] = mx2; }
        __syncthreads();
        if (threadIdx.x == 0) {
            mnmx[0] = fminf(fminf(wmn2[0], wmn2[1]), fminf(wmn2[2], wmn2[3]));
            mnmx[1] = fmaxf(fmaxf(wmx2[0], wmx2[1]), fmaxf(wmx2[2], wmx2[3]));
        }
        __syncthreads();
    }
    float mnv = mnmx[0], mxv = mnmx[1];
    float width = (mxv > mnv) ? (mxv - mnv) : 1.0f;
    float scale = 16.0f / width;
    float nbias = -mnv * scale;
    const unsigned short* arow = a1 + ((size_t)(by * 128 + (w >> 1) * 64 + r16)) * 32 + kg;
    bf16x8 afr[4];
#pragma unroll
    for (int m = 0; m < 4; ++m) afr[m] = *(const bf16x8*)(arow + m * 16 * 32);
    unsigned h4_0 = 0, h4_1 = 0, h4_2 = 0, h4_3 = 0;
#pragma unroll
    for (int t = 0; t < SIM_CHUNK; ++t) {
        int bx = ch * SIM_CHUNK + t;
        const unsigned short* brow = a2 + ((size_t)(bx * 128 + (w & 1) * 64 + r16)) * 32 + kg;
        bf16x8 bfr[4];
#pragma unroll
        for (int n = 0; n < 4; ++n) bfr[n] = *(const bf16x8*)(brow + n * 16 * 32);
        f32x4 zero = {0.f, 0.f, 0.f, 0.f};
        f32x4 acc[4][4];
#pragma unroll
        for (int m = 0; m < 4; ++m)
#pragma unroll
            for (int n = 0; n < 4; ++n)
                acc[m][n] =
                    __builtin_amdgcn_mfma_f32_16x16x32_bf16(afr[m], bfr[n], zero, 0, 0, 0);
#pragma unroll
        for (int m = 0; m < 4; ++m)
#pragma unroll
            for (int n = 0; n < 4; ++n)
#pragma unroll
                for (int e = 0; e < 4; ++e) {
                    float v = acc[m][n][e];
                    int bin = (int)fmaf(v, scale, nbias);
                    bin = bin < 0 ? 0 : (bin > 15 ? 15 : bin);
                    unsigned wbit = 1u << ((bin & 3) << 3);
                    int hi = bin >> 2;
                    h4_0 += (hi == 0) ? wbit : 0u;
                    h4_1 += (hi == 1) ? wbit : 0u;
                    h4_2 += (hi == 2) ? wbit : 0u;
                    h4_3 += (hi == 3) ? wbit : 0u;
                }
    }
    unsigned hh[8];
    hh[0] = h4_0 & 0x00FF00FFu; hh[1] = (h4_0 >> 8) & 0x00FF00FFu;
    hh[2] = h4_1 & 0x00FF00FFu; hh[3] = (h4_1 >> 8) & 0x00FF00FFu;
    hh[4] = h4_2 & 0x00FF00FFu; hh[5] = (h4_2 >> 8) & 0x00FF00FFu;
    hh[6] = h4_3 & 0x00FF00FFu; hh[7] = (h4_3 >> 8) & 0x00FF00FFu;
#pragma unroll
    for (int off = 1; off < 64; off <<= 1) {
#pragma unroll
        for (int q = 0; q < 8; ++q) hh[q] += (unsigned)__shfl_xor((int)hh[q], off);
    }
    __syncthreads();
    if (lane < 16) {
        int q = lane >> 2, r = lane & 3;
        unsigned word = hh[2 * q + (r & 1)];
        unsigned val = (r < 2) ? (word & 0xFFFFu) : (word >> 16);
        atomicAdd(&hs[lane], val);
    }
    __syncthreads();
    if (threadIdx.x < 16)
        pbhist[(size_t)blockIdx.x * 16 + threadIdx.x] = hs[threadIdx.x];
}

// ========= hist reduce + NTN + MLP head ====================================
__global__ __launch_bounds__(256) void ntn_final(
    const float* __restrict__ p12, const float* __restrict__ Wt,
    const float* __restrict__ V, const float* __restrict__ bt,
    const unsigned* __restrict__ pbhist, int nblk,
    const float* __restrict__ fc1W, const float* __restrict__ fc1b,
    const float* __restrict__ fc2W, const float* __restrict__ fc2b,
    const float* __restrict__ fc3W, const float* __restrict__ fc3b,
    const float* __restrict__ scW, const float* __restrict__ scb,
    const float* __restrict__ avg_v, float* __restrict__ out) {
    __shared__ float p1l[32], p2l[32];
    __shared__ float scp[16][17];
    __shared__ unsigned hs[16];
    __shared__ float sc[16];
    __shared__ float sfeat[32];
    __shared__ float h1s[16];
    int t = threadIdx.x;
    if (t < 16) hs[t] = 0;
    if (t < 32) p1l[t] = p12[t];
    else if (t < 64) p2l[t - 32] = p12[t];
    __syncthreads();
    {
        const uint4* pb = (const uint4*)pbhist;
        int total = nblk * 4;
        uint4 a = {0u, 0u, 0u, 0u};
        for (int i = t; i < total; i += 256) {
            uint4 v = pb[i];
            a.x += v.x; a.y += v.y; a.z += v.z; a.w += v.w;
        }
#pragma unroll
        for (int off = 4; off < 64; off <<= 1) {
            a.x += (unsigned)__shfl_xor((int)a.x, off);
            a.y += (unsigned)__shfl_xor((int)a.y, off);
            a.z += (unsigned)__shfl_xor((int)a.z, off);
            a.w += (unsigned)__shfl_xor((int)a.w, off);
        }
        int lane = t & 63;
        if (lane < 4) {
            atomicAdd(&hs[lane * 4 + 0], a.x);
            atomicAdd(&hs[lane * 4 + 1], a.y);
            atomicAdd(&hs[lane * 4 + 2], a.z);
            atomicAdd(&hs[lane * 4 + 3], a.w);
        }
    }
    {
        int k = t & 15, dp = t >> 4;
        float s = 0.f;
#pragma unroll
        for (int dd = 0; dd < 2; ++dd) {
            int d = dp * 2 + dd;
            float a = p1l[d];
            for (int e = 0; e < 32; ++e)
                s = fmaf(a * p2l[e], Wt[(d * 32 + e) * 16 + k], s);
        }
        scp[dp][k] = s;
    }
    __syncthreads();
    if (t < 16) {
        float s = 0.f;
#pragma unroll
        for (int dp = 0; dp < 16; ++dp) s += scp[dp][t];
        float bl = 0.f;
        for (int m = 0; m < 32; ++m) bl = fmaf(V[t * 64 + m], p1l[m], bl);
        for (int m = 0; m < 32; ++m) bl = fmaf(V[t * 64 + 32 + m], p2l[m], bl);
        sc[t] = fmaxf(s + bl + bt[t], 0.f);
    }
    __syncthreads();
    if (t < 16) sfeat[t] = sc[t];
    if (t == 16) {
        unsigned tot = 0;
        for (int b = 0; b < 16; ++b) tot += hs[b];
        float ftot = (float)tot;
        for (int b = 0; b < 16; ++b) sfeat[16 + b] = (float)hs[b] / ftot;
    }
    __syncthreads();
    if (t < 16) {
        float a = fc1b[t];
        for (int m = 0; m < 32; ++m) a = fmaf(sfeat[m], fc1W[m * 16 + t], a);
        h1s[t] = fmaxf(a, 0.f);
    }
    __syncthreads();
    if (t != 0) return;
    float h2[8];
    for (int r = 0; r < 8; ++r) {
        float a = fc2b[r];
        for (int m = 0; m < 16; ++m) a = fmaf(h1s[m], fc2W[m * 8 + r], a);
        h2[r] = fmaxf(a, 0.f);
    }
    float h3[4];
    for (int r = 0; r < 4; ++r) {
        float a = fc3b[r];
        for (int m = 0; m < 8; ++m) a = fmaf(h2[m], fc3W[m * 4 + r], a);
        h3[r] = fmaxf(a, 0.f);
    }
    float z = scb[0];
    for (int m = 0; m < 4; ++m) z = fmaf(h3[m], scW[m], z);
    float sig = 1.f / (1.f + expf(-z));
    out[0] = sig;
    out[1] = -logf(sig) * avg_v[0];
}

// ---------------------------------------------------------------------------
extern "C" void kernel_launch(void* const* d_in, const int* in_sizes, int n_in,
                              void* d_out, int out_size, void* d_ws, size_t ws_size,
                              hipStream_t stream) {
    (void)n_in; (void)out_size; (void)ws_size;
    const int* ei1 = (const int*)d_in[0];
    const int* ei2 = (const int*)d_in[1];
    const float* feat1 = (const float*)d_in[2];
    const float* feat2 = (const float*)d_in[3];
    const float* avg_v = (const float*)d_in[4];
    const float* W1 = (const float*)d_in[5];
    const float* b1 = (const float*)d_in[6];
    const float* W2 = (const float*)d_in[7];
    const float* b2 = (const float*)d_in[8];
    const float* W3 = (const float*)d_in[9];
    const float* b3 = (const float*)d_in[10];
    const float* Wa = (const float*)d_in[11];
    const float* Wt = (const float*)d_in[12];
    const float* V = (const float*)d_in[13];
    const float* bt = (const float*)d_in[14];
    const float* fc1W = (const float*)d_in[15];
    const float* fc1b = (const float*)d_in[16];
    const float* fc2W = (const float*)d_in[17];
    const float* fc2b = (const float*)d_in[18];
    const float* fc3W = (const float*)d_in[19];
    const float* fc3b = (const float*)d_in[20];
    const float* scW = (const float*)d_in[21];
    const float* scb = (const float*)d_in[22];

    const int E = in_sizes[0] / 2;
    const int N = in_sizes[2] / 64;
    const int nb = N / 128;
    const int nchunk = nb / SIM_CHUNK;
    const int NSIM = nb * nchunk;

    // ---- workspace layout: gsum | p12 | cnt contiguous => single zero pass ----
    char* w = (char*)d_ws;
    size_t off = 0;
    auto take = [&](size_t bytes) -> char* {
        char* p = w + off;
        off = (off + bytes + 255) & ~(size_t)255;
        return p;
    };
    float* gsum = (float*)take((size_t)2 * GS_REP * 32 * GS_PAD * 4);  // zero start
    float* p12 = (float*)take(64 * 4);
    int* cnt = (int*)take((size_t)2 * N * 4);                          // zero end
    float* af = (float*)take((size_t)2 * N * 32 * 4);
    unsigned short* afbf = (unsigned short*)take((size_t)2 * N * 32 * 2);
    float2* pbmm = (float2*)take((size_t)NSIM * 8);
    unsigned* pbhist = (unsigned*)take((size_t)NSIM * 16 * 4);
    float* dinv = (float*)take((size_t)2 * N * 4);
    int* offs = (int*)take((size_t)2 * (N + 1) * 4);
    int* cursor = (int*)take((size_t)2 * N * 4);
    int* esrc = (int*)take((size_t)2 * E * 4);
    float* t1 = (float*)take((size_t)2 * N * 64 * 4);
    float* t3 = (float*)take((size_t)2 * N * 32 * 4);

    size_t zbytes = ((char*)cnt + (size_t)2 * N * 4) - (char*)gsum;
    int zn4 = (int)(zbytes / 16);

    // ---- parallel CSR build ----
    zero_ws<<<(zn4 + 255) / 256, 256, 0, stream>>>((float4*)gsum, zn4);
    count_tgt<<<dim3((E + 255) / 256, 2), 256, 0, stream>>>(ei1 + E, ei2 + E, cnt, N, E);
    scan_offsets<<<2, 1024, 0, stream>>>(cnt, offs, cursor, dinv, N);
    scatter_src<<<dim3((E + 255) / 256, 2), 256, 0, stream>>>(ei1, ei2, ei1 + E, ei2 + E,
                                                              cursor, esrc, N, E);

    // ---- fused GCN pipeline (16-row tiles, 4 blocks/CU) ----
    fusedA<<<dim3(N / 16, 2), 256, 0, stream>>>(feat1, feat2, W1, b1, W2, t1, offs, esrc,
                                                dinv, N, E);
    fusedB<<<dim3(N / 16, 2), 256, 0, stream>>>(t1, b2, W3, t3, offs, esrc, dinv, N, E);
    agg3_pool<<<dim3(N / 32, 2), 256, 0, stream>>>(t3, t3 + (size_t)N * 32, offs, esrc,
                                                   dinv, b3, af, afbf, gsum, N, E);
    simA<<<NSIM + (N / 256) * 2, 256, 0, stream>>>(afbf, af, gsum, Wa, p12, pbmm, N, NSIM);
    simB<<<NSIM, 256, 0, stream>>>(afbf, afbf + (size_t)N * 32, N, NSIM, pbmm, pbhist);
    ntn_final<<<1, 256, 0, stream>>>(p12, Wt, V, bt, pbhist, NSIM, fc1W, fc1b, fc2W, fc2b,
                                     fc3W, fc3b, scW, scb, avg_v, (float*)d_out);
}